// Round 3
// baseline (599.830 us; speedup 1.0000x reference)
//
#include <hip/hip_runtime.h>
#include <cmath>

#define KNN 20
#define NPTS 4096
#define BATCH 2
#define SLOPE 0.2f
#define BNEPS 1e-5
#define GTK 16
#define MAXCAND 256

typedef unsigned short u16;
typedef __attribute__((ext_vector_type(8))) short bf16x8;
typedef __attribute__((ext_vector_type(4))) float f32x4;
typedef _Float16 h8 __attribute__((ext_vector_type(8)));
typedef _Float16 h4 __attribute__((ext_vector_type(4)));

static __device__ __host__ inline int imin(int a, int b) { return a < b ? a : b; }

__device__ inline u16 f2bf(float v) {
  unsigned x = __float_as_uint(v);
  unsigned rr = x + 0x7fff + ((x >> 16) & 1);
  return (u16)(rr >> 16);
}

// ---------------- utility kernels ----------------
// x (B,3,N) -> xb (B,N,3)
__global__ void xtrans_kernel(const float* __restrict__ x, float* __restrict__ xb) {
  int i = blockIdx.x * 256 + threadIdx.x;
  if (i < BATCH * 3 * NPTS) {
    int b = i / (3 * NPTS);
    int r = i - b * 3 * NPTS;
    int c = r / NPTS;
    int n = r - c * NPTS;
    xb[((size_t)b * NPTS + n) * 3 + c] = x[i];
  }
}

// W (O, 2C) -> U (C, 2O): U[j][o]=W[o][j]; U[j][O+o]=W[o][C+j]-W[o][j]
__global__ void uprep_kernel(const float* __restrict__ W, float* __restrict__ U, int O, int C) {
  int i = blockIdx.x * 256 + threadIdx.x;
  if (i < C * O) {
    int j = i / O, o = i - j * O;
    float w1 = W[(size_t)o * 2 * C + j];
    float w2 = W[(size_t)o * 2 * C + C + j];
    U[(size_t)j * 2 * O + o] = w1;
    U[(size_t)j * 2 * O + O + o] = w2 - w1;
  }
}

// squared norms per point (fp64 accumulate, fp32 store — candidate pass only)
__global__ void xx_kernel(const float* __restrict__ X, int stride, int C, float* __restrict__ xx) {
  int i = blockIdx.x * 256 + threadIdx.x;
  if (i < BATCH * NPTS) {
    const float* r = X + (size_t)i * stride;
    double s = 0.0;
    for (int c = 0; c < C; ++c) s += (double)r[c] * (double)r[c];
    xx[i] = (float)s;
  }
}

// fp32 -> bf16 (RNE), 4 elements/thread
__global__ void tobf16_kernel(const float* __restrict__ src, u16* __restrict__ dst, int n4) {
  int i = blockIdx.x * 256 + threadIdx.x;
  if (i < n4) {
    float4 v = *(const float4*)&src[(size_t)i * 4];
    unsigned o[4];
#pragma unroll
    for (int j = 0; j < 4; ++j) o[j] = f2bf(((const float*)&v)[j]);
    uint2 pk;
    pk.x = o[0] | (o[1] << 16);
    pk.y = o[2] | (o[3] << 16);
    *(uint2*)&dst[(size_t)i * 4] = pk;
  }
}

// fp32 X (row-major, lda) -> split hi/lo bf16 (row-major, C), 4 cols/thread
__global__ void tosplit_kernel(const float* __restrict__ X, int lda, int C,
                               u16* __restrict__ hi, u16* __restrict__ lo, int ngroups) {
  int g = blockIdx.x * 256 + threadIdx.x;
  if (g >= ngroups) return;
  int perRow = C >> 2;
  int r = g / perRow;
  int cq = (g - r * perRow) * 4;
  float4 v = *(const float4*)&X[(size_t)r * lda + cq];
  unsigned ho[4], lo_[4];
#pragma unroll
  for (int j = 0; j < 4; ++j) {
    float f = ((const float*)&v)[j];
    u16 h = f2bf(f);
    float hv = __uint_as_float(((unsigned)h) << 16);
    ho[j] = h;
    lo_[j] = f2bf(f - hv);
  }
  uint2 ph, pl;
  ph.x = ho[0] | (ho[1] << 16);
  ph.y = ho[2] | (ho[3] << 16);
  pl.x = lo_[0] | (lo_[1] << 16);
  pl.y = lo_[2] | (lo_[3] << 16);
  size_t di = (size_t)r * C + cq;
  *(uint2*)&hi[di] = ph;
  *(uint2*)&lo[di] = pl;
}

// ---------------- generic 128x128 fp32 GEMM, 8x8 micro (single-buffered) ----------------
// C[M x N] = A[M x K] * (BT ? B[N x K]^T : B[K x N]); DIST epilogue writes fp16.
template <bool BT, bool DIST>
__global__ __launch_bounds__(256) void gemm128(const float* __restrict__ A, int lda,
                                               const float* __restrict__ B, int ldb,
                                               void* __restrict__ Cout, int ldc, int K,
                                               const float* __restrict__ xxA,
                                               const float* __restrict__ xxB) {
  __shared__ __align__(16) float sA[GTK][144];
  __shared__ __align__(16) float sB[GTK][144];
  int t = threadIdx.x;
  int tx = t & 15, ty = t >> 4;
  int row0 = blockIdx.y * 128, col0 = blockIdx.x * 128;
  float acc[8][8] = {};

  for (int k0 = 0; k0 < K; k0 += GTK) {
    bool fast = (k0 + GTK <= K);
    if (fast) {
#pragma unroll
      for (int it = 0; it < 2; ++it) {
        int i = t + it * 256;
        int r = i >> 2, q = i & 3;
        const float4 av = *(const float4*)&A[(size_t)(row0 + r) * lda + k0 + q * 4];
        int pr = r + ((r >> 5) << 2);
        sA[q * 4 + 0][pr] = av.x;
        sA[q * 4 + 1][pr] = av.y;
        sA[q * 4 + 2][pr] = av.z;
        sA[q * 4 + 3][pr] = av.w;
      }
    } else {
#pragma unroll
      for (int it = 0; it < 2; ++it) {
        int i = t + it * 256;
        int r = i >> 2, q = i & 3;
        int pr = r + ((r >> 5) << 2);
#pragma unroll
        for (int j = 0; j < 4; ++j) {
          int k = q * 4 + j;
          sA[k][pr] = (k0 + k < K) ? A[(size_t)(row0 + r) * lda + k0 + k] : 0.f;
        }
      }
    }
    if (BT) {
      if (fast) {
#pragma unroll
        for (int it = 0; it < 2; ++it) {
          int i = t + it * 256;
          int r = i >> 2, q = i & 3;
          const float4 bv = *(const float4*)&B[(size_t)(col0 + r) * ldb + k0 + q * 4];
          int pr = r + ((r >> 5) << 2);
          sB[q * 4 + 0][pr] = bv.x;
          sB[q * 4 + 1][pr] = bv.y;
          sB[q * 4 + 2][pr] = bv.z;
          sB[q * 4 + 3][pr] = bv.w;
        }
      } else {
#pragma unroll
        for (int it = 0; it < 2; ++it) {
          int i = t + it * 256;
          int r = i >> 2, q = i & 3;
          int pr = r + ((r >> 5) << 2);
#pragma unroll
          for (int j = 0; j < 4; ++j) {
            int k = q * 4 + j;
            sB[k][pr] = (k0 + k < K) ? B[(size_t)(col0 + r) * ldb + k0 + k] : 0.f;
          }
        }
      }
    } else {
#pragma unroll
      for (int it = 0; it < 2; ++it) {
        int i = t + it * 256;
        int k = i >> 5, nq = (i & 31) * 4;
        int pc = nq + ((nq >> 5) << 2);
        float4 bv = make_float4(0.f, 0.f, 0.f, 0.f);
        if (k0 + k < K) bv = *(const float4*)&B[(size_t)(k0 + k) * ldb + col0 + nq];
        *(float4*)&sB[k][pc] = bv;
      }
    }
    __syncthreads();
    int prA = ty * 8 + ((ty >> 2) << 2);
    int prB = tx * 8 + ((tx >> 2) << 2);
#pragma unroll
    for (int kk = 0; kk < GTK; ++kk) {
      float a[8], b[8];
      *(float4*)&a[0] = *(const float4*)&sA[kk][prA];
      *(float4*)&a[4] = *(const float4*)&sA[kk][prA + 4];
      *(float4*)&b[0] = *(const float4*)&sB[kk][prB];
      *(float4*)&b[4] = *(const float4*)&sB[kk][prB + 4];
#pragma unroll
      for (int i = 0; i < 8; ++i)
#pragma unroll
        for (int j = 0; j < 8; ++j) acc[i][j] += a[i] * b[j];
    }
    __syncthreads();
  }

  if (DIST) {
    _Float16* Ch = (_Float16*)Cout;
#pragma unroll
    for (int i = 0; i < 8; ++i) {
      int gr = row0 + ty * 8 + i;
      float xa = xxA[gr];
      h8 o;
#pragma unroll
      for (int j = 0; j < 8; ++j) {
        int gc = col0 + tx * 8 + j;
        o[j] = (_Float16)(2.f * acc[i][j] - xa - xxB[gc]);
      }
      *(h8*)&Ch[(size_t)gr * ldc + col0 + tx * 8] = o;
    }
  } else {
    float* Cf = (float*)Cout;
#pragma unroll
    for (int i = 0; i < 8; ++i) {
      int gr = row0 + ty * 8 + i;
#pragma unroll
      for (int jq = 0; jq < 2; ++jq) {
        float4 o;
#pragma unroll
        for (int j = 0; j < 4; ++j) ((float*)&o)[j] = acc[i][jq * 4 + j];
        *(float4*)&Cf[(size_t)gr * ldc + col0 + tx * 8 + jq * 4] = o;
      }
    }
  }
}

// ---------------- split-bf16 MFMA symmetric dist: lower-triangle tiles, mirrored write ----
// <x,y> = hi.hi + hi.lo + lo.hi (3 chained bf16 MFMAs, fp32 acc; lo.lo term ~2^-16 dropped).
// Epilogue: fp16 tile in LDS (rows padded to 136 u16), coalesced h8 writes both orientations.
// grid (ntile, nbatch). Fragment maps identical to fc_mfma (m89-verified).
// LDS layout: 4 slabs of 5120 u16 at offsets a*5120 (Ahi, Alo, Bhi, Blo), rows of 40 u16.
__global__ __launch_bounds__(256) void dist_sym_mfma_kernel(const u16* __restrict__ Xhi,
                                                            const u16* __restrict__ Xlo, int K,
                                                            const float* __restrict__ xx,
                                                            _Float16* __restrict__ dist,
                                                            size_t dstride) {
  __shared__ __align__(16) u16 smem[20544];  // staging 4x128x40 (40960 B) / tile 128x136 (34816 B)
  int t = threadIdx.x;
  int lane = t & 63, wave = t >> 6;
  const u16* xh = Xhi + (size_t)blockIdx.y * NPTS * K;
  const u16* xl = Xlo + (size_t)blockIdx.y * NPTS * K;
  const float* xxv = xx + (size_t)blockIdx.y * NPTS;
  _Float16* db = dist + (size_t)blockIdx.y * dstride;
  int l = blockIdx.x;
  int bi = (int)((sqrtf(8.f * (float)l + 1.f) - 1.f) * 0.5f);
  while ((bi + 1) * (bi + 2) / 2 <= l) ++bi;
  while (bi * (bi + 1) / 2 > l) --bi;
  int bj = l - bi * (bi + 1) / 2;
  int row0 = bi * 128, col0 = bj * 128;
  int wr = (wave >> 1) * 64, wc = (wave & 1) * 64;
  int m = lane & 15, q = lane >> 4;
  f32x4 acc[4][4];
#pragma unroll
  for (int i = 0; i < 4; ++i)
#pragma unroll
    for (int j = 0; j < 4; ++j) acc[i][j] = (f32x4){0.f, 0.f, 0.f, 0.f};

  for (int k0 = 0; k0 < K; k0 += 32) {
#pragma unroll
    for (int it = 0; it < 8; ++it) {
      int e = t + it * 256;
      int a = e >> 9, idx = e & 511;
      int r = idx >> 2, qq = idx & 3;
      const u16* src = (a == 0 || a == 2) ? xh : xl;
      int base = (a < 2) ? row0 : col0;
      *(uint4*)&smem[a * 5120 + r * 40 + qq * 8] =
          *(const uint4*)&src[(size_t)(base + r) * K + k0 + qq * 8];
    }
    __syncthreads();
    bf16x8 ah[4], al[4], bh[4], bl[4];
#pragma unroll
    for (int i = 0; i < 4; ++i) {
      ah[i] = *(const bf16x8*)&smem[0 * 5120 + (wr + i * 16 + m) * 40 + q * 8];
      al[i] = *(const bf16x8*)&smem[1 * 5120 + (wr + i * 16 + m) * 40 + q * 8];
    }
#pragma unroll
    for (int j = 0; j < 4; ++j) {
      bh[j] = *(const bf16x8*)&smem[2 * 5120 + (wc + j * 16 + m) * 40 + q * 8];
      bl[j] = *(const bf16x8*)&smem[3 * 5120 + (wc + j * 16 + m) * 40 + q * 8];
    }
#pragma unroll
    for (int i = 0; i < 4; ++i)
#pragma unroll
      for (int j = 0; j < 4; ++j) {
        acc[i][j] = __builtin_amdgcn_mfma_f32_16x16x32_bf16(ah[i], bh[j], acc[i][j], 0, 0, 0);
        acc[i][j] = __builtin_amdgcn_mfma_f32_16x16x32_bf16(ah[i], bl[j], acc[i][j], 0, 0, 0);
        acc[i][j] = __builtin_amdgcn_mfma_f32_16x16x32_bf16(al[i], bh[j], acc[i][j], 0, 0, 0);
      }
    __syncthreads();
  }

  // DIST transform -> fp16 LDS tile (reuses staging smem; all reads drained by loop-end sync)
  _Float16* tile = (_Float16*)smem;
  {
    float xbv[4];
#pragma unroll
    for (int j = 0; j < 4; ++j) xbv[j] = xxv[col0 + wc + j * 16 + m];
#pragma unroll
    for (int i = 0; i < 4; ++i)
#pragma unroll
      for (int reg = 0; reg < 4; ++reg) {
        int r = wr + i * 16 + q * 4 + reg;
        float xa = xxv[row0 + r];
#pragma unroll
        for (int j = 0; j < 4; ++j)
          tile[r * 136 + wc + j * 16 + m] = (_Float16)(2.f * acc[i][j][reg] - xa - xbv[j]);
      }
  }
  __syncthreads();
  // direct tile (row0, col0): coalesced h8 per 8-col segment
  for (int e = t; e < 2048; e += 256) {
    int r = e >> 4, seg = e & 15;
    *(h8*)&db[(size_t)(row0 + r) * NPTS + col0 + seg * 8] = *(const h8*)&tile[r * 136 + seg * 8];
  }
  // mirrored tile (col0, row0): transposed LDS reads, coalesced global h8 writes
  if (bi != bj) {
    for (int e = t; e < 2048; e += 256) {
      int c = e >> 4, seg = e & 15;
      h8 o;
#pragma unroll
      for (int i = 0; i < 8; ++i) o[i] = tile[(seg * 8 + i) * 136 + c];
      *(h8*)&db[(size_t)(col0 + c) * NPTS + row0 + seg * 8] = o;
    }
  }
}

// ---------------- bf16 MFMA FC: C[8192x1024] = A[8192x512] * B[1024x512]^T ----------------
// Epilogue additionally emits per-block fp64 column sum/sumsq partials (replaces colstats):
// block (cx,ry) owns rows [ry*128,+128) x cols [cx*128,+128); writes pbuf[ry*2048 + col] (sum)
// and pbuf[ry*2048 + 1024 + col] (sumsq) — same layout bn_reduce_finalize(nblk=64) consumes.
__global__ __launch_bounds__(256) void fc_mfma_kernel(const u16* __restrict__ A,
                                                      const u16* __restrict__ B,
                                                      float* __restrict__ C,
                                                      double* __restrict__ pbuf) {
  __shared__ u16 sA[128][56];
  __shared__ u16 sB[128][56];
  __shared__ double sred1[4][64];
  __shared__ double sred2[4][64];
  int t = threadIdx.x;
  int lane = t & 63, wave = t >> 6;
  int row0 = blockIdx.y * 128, col0 = blockIdx.x * 128;
  int wr = (wave >> 1) * 64, wc = (wave & 1) * 64;
  int m = lane & 15, q = lane >> 4;
  f32x4 acc[4][4];
#pragma unroll
  for (int i = 0; i < 4; ++i)
#pragma unroll
    for (int j = 0; j < 4; ++j) acc[i][j] = (f32x4){0.f, 0.f, 0.f, 0.f};
  for (int k0 = 0; k0 < 512; k0 += 32) {
#pragma unroll
    for (int it = 0; it < 2; ++it) {
      int i = t + it * 256;
      int r = i >> 2, ch = (i & 3) * 8;
      *(uint4*)&sA[r][ch] = *(const uint4*)&A[(size_t)(row0 + r) * 512 + k0 + ch];
      *(uint4*)&sB[r][ch] = *(const uint4*)&B[(size_t)(col0 + r) * 512 + k0 + ch];
    }
    __syncthreads();
    bf16x8 af[4], bf[4];
#pragma unroll
    for (int i = 0; i < 4; ++i) af[i] = *(const bf16x8*)&sA[wr + i * 16 + m][q * 8];
#pragma unroll
    for (int j = 0; j < 4; ++j) bf[j] = *(const bf16x8*)&sB[wc + j * 16 + m][q * 8];
#pragma unroll
    for (int i = 0; i < 4; ++i)
#pragma unroll
      for (int j = 0; j < 4; ++j)
        acc[i][j] = __builtin_amdgcn_mfma_f32_16x16x32_bf16(af[i], bf[j], acc[i][j], 0, 0, 0);
    __syncthreads();
  }
#pragma unroll
  for (int i = 0; i < 4; ++i)
#pragma unroll
    for (int j = 0; j < 4; ++j)
#pragma unroll
      for (int reg = 0; reg < 4; ++reg)
        C[(size_t)(row0 + wr + i * 16 + q * 4 + reg) * 1024 + col0 + wc + j * 16 + m] =
            acc[i][j][reg];

  // ---- fused column stats (fp64): per-thread 16 rows, q-group shuffle, wave-pair combine ----
#pragma unroll
  for (int j = 0; j < 4; ++j) {
    double s1 = 0.0, s2 = 0.0;
#pragma unroll
    for (int i = 0; i < 4; ++i)
#pragma unroll
      for (int reg = 0; reg < 4; ++reg) {
        double v = (double)acc[i][j][reg];
        s1 += v;
        s2 += v * v;
      }
    // reduce across q (lanes q*16+m, q=0..3): xor 16 then 32 keeps m fixed
    s1 += __shfl_xor(s1, 16);
    s2 += __shfl_xor(s2, 16);
    s1 += __shfl_xor(s1, 32);
    s2 += __shfl_xor(s2, 32);
    if (q == 0) {
      sred1[wave][j * 16 + m] = s1;
      sred2[wave][j * 16 + m] = s2;
    }
  }
  __syncthreads();
  if (t < 128) {
    int p = t >> 6, u = t & 63;  // p: wc half (waves p and p+2), u = j*16+m
    double a = sred1[p][u] + sred1[p + 2][u];
    double b = sred2[p][u] + sred2[p + 2][u];
    int gcol = col0 + p * 64 + u;
    pbuf[(size_t)blockIdx.y * 2048 + gcol] = a;
    pbuf[(size_t)blockIdx.y * 2048 + 1024 + gcol] = b;
  }
}

// ---------------- shared top-k selection helpers ----------------
__device__ inline bool comp_less(double v, int i, double ov, int oi) {
  return (v < ov) || (v == ov && i > oi);
}

// ---------------- fast top-k: threshold filter (fp16 dist) + fp64 rescore + bitonic sort ---
__global__ __launch_bounds__(256) void topk_fast_kernel(const _Float16* __restrict__ dist,
                                                        size_t dstride,
                                                        const float* __restrict__ Xb,
                                                        size_t xstride, int lda, int C,
                                                        int* __restrict__ idxout, size_t istride,
                                                        int n0, int rows) {
  __shared__ int scand[4][MAXCAND];
  int wave = threadIdx.x >> 6, lane = threadIdx.x & 63;
  int row = blockIdx.x * 4 + wave;
  if (row >= rows) return;
  const _Float16* distb = dist + (size_t)blockIdx.y * dstride;
  const float* Xbb = Xb + (size_t)blockIdx.y * xstride;
  int* idxb = idxout + (size_t)blockIdx.y * istride;
  const _Float16* d = distb + (size_t)row * NPTS;
  float v[16][4];
  float lmax = -__builtin_inff();
#pragma unroll
  for (int s = 0; s < 16; ++s) {
    h4 hv = *(const h4*)&d[s * 256 + lane * 4];
#pragma unroll
    for (int c = 0; c < 4; ++c) {
      v[s][c] = (float)hv[c];
      lmax = fmaxf(lmax, v[s][c]);
    }
  }

  float sv = lmax;
  for (int k = 2; k <= 64; k <<= 1) {
    for (int j = k >> 1; j > 0; j >>= 1) {
      float ov = __shfl_xor(sv, j);
      bool up = ((lane & k) == 0);
      bool lower = ((lane & j) == 0);
      bool mineLess = sv < ov;
      bool keepMine = (up == lower) ? mineLess : !mineLess;
      sv = keepMine ? sv : ov;
    }
  }
  float T = __shfl(sv, 44);

  int myCnt = 0;
#pragma unroll
  for (int s = 0; s < 16; ++s)
#pragma unroll
    for (int c = 0; c < 4; ++c) myCnt += (v[s][c] >= T) ? 1 : 0;
  int ofs = myCnt;
  for (int dlt = 1; dlt < 64; dlt <<= 1) {
    int o = __shfl_up(ofs, dlt);
    if (lane >= dlt) ofs += o;
  }
  int total = __shfl(ofs, 63);
  ofs -= myCnt;
  int w = ofs;
#pragma unroll
  for (int s = 0; s < 16; ++s)
#pragma unroll
    for (int c = 0; c < 4; ++c) {
      if (v[s][c] >= T) {
        if (w < MAXCAND) scand[wave][w] = s * 256 + lane * 4 + c;
        ++w;
      }
    }
  int cnt = imin(total, MAXCAND);
  int gn = n0 + row;
  const float* crow = Xbb + (size_t)gn * lda;
  int nch = (cnt + 63) >> 6;

  double runV = -__builtin_inf();
  int runI = 0x7fffffff;
  for (int ch = 0; ch < nch; ++ch) {
    int slot = ch * 64 + lane;
    int m = (slot < cnt) ? scand[wave][slot] : -1;
    double val = -__builtin_inf();
    int vi = 0x7fffffff;
    if (m >= 0) {
      const float* mrow = Xbb + (size_t)m * lda;
      double dd = 0.0;
      for (int c = 0; c < C; c += 4) {
        float4 a = *(const float4*)&crow[c];
        float4 b = *(const float4*)&mrow[c];
#pragma unroll
        for (int qq = 0; qq < 4; ++qq) {
          double df = (double)((const float*)&a)[qq] - (double)((const float*)&b)[qq];
          dd = fma(df, df, dd);
        }
      }
      val = -dd;
      vi = m;
    }
    for (int k = 2; k <= 64; k <<= 1) {
      for (int j = k >> 1; j > 0; j >>= 1) {
        double ov = __shfl_xor(val, j);
        int oi = __shfl_xor(vi, j);
        bool up = ((lane & k) == 0);
        bool lower = ((lane & j) == 0);
        bool mineLess = comp_less(val, vi, ov, oi);
        bool keepMine = (up == lower) ? mineLess : !mineLess;
        if (!keepMine) { val = ov; vi = oi; }
      }
    }
    if (ch == 0) {
      runV = val;
      runI = vi;
    } else {
      double rv = __shfl(val, 63 - lane);
      int ri = __shfl(vi, 63 - lane);
      if (comp_less(runV, runI, rv, ri)) { runV = rv; runI = ri; }
      for (int j = 32; j > 0; j >>= 1) {
        double ov = __shfl_xor(runV, j);
        int oi = __shfl_xor(runI, j);
        bool lower = ((lane & j) == 0);
        bool mineLess = comp_less(runV, runI, ov, oi);
        bool keepMine = lower ? mineLess : !mineLess;
        if (!keepMine) { runV = ov; runI = oi; }
      }
    }
  }
  if (lane >= 44) idxb[(size_t)gn * KNN + (63 - lane)] = runI;
}

// ---------------- fused layer-1 kNN (C=3): whole point set in LDS ----------------
// 512 threads = 8 waves/block, 8 rows/block. LDS = 48K xyz + 4K u16-scand = 52K
// -> 3 blocks/CU = 24 waves/CU. Distances RECOMPUTED in count/write passes (no v[16][4]
// cache) to keep VGPR <= ~64 so VGPR doesn't cap below the 24-wave LDS limit. negd3()
// uses fixed fmaf ordering so all three passes compute bit-identical values (harness-
// verified in an earlier round). NO min-waves launch bound (forcing it clamps VGPR to
// 32 and spills ~600 MB/dispatch to scratch).
__device__ __forceinline__ float negd3(float cx, float cy, float cz,
                                       const float* __restrict__ xs,
                                       const float* __restrict__ ys,
                                       const float* __restrict__ zs, int m) {
  float dx = cx - xs[m];
  float dy = cy - ys[m];
  float dz = cz - zs[m];
  return -fmaf(dx, dx, fmaf(dy, dy, dz * dz));
}

__global__ __launch_bounds__(512) void dist3_topk_kernel(const float* __restrict__ Xb,
                                                         int* __restrict__ idxout) {
  __shared__ float xs[NPTS], ys[NPTS], zs[NPTS];
  __shared__ u16 scand[8][MAXCAND];
  int t = threadIdx.x;
  const float* Xbb = Xb + (size_t)blockIdx.y * NPTS * 3;
  for (int i = t; i < NPTS * 3; i += 512) {
    int n = i / 3, c = i - n * 3;
    float v = Xbb[i];
    if (c == 0) xs[n] = v;
    else if (c == 1) ys[n] = v;
    else zs[n] = v;
  }
  __syncthreads();
  int wave = t >> 6, lane = t & 63;
  int row = blockIdx.x * 8 + wave;
  float cx = xs[row], cy = ys[row], cz = zs[row];

  // pass 1: per-lane max over this lane's 64 elements (m = s*256 + c*64 + lane)
  float lmax = -__builtin_inff();
#pragma unroll
  for (int s = 0; s < 16; ++s)
#pragma unroll
    for (int c = 0; c < 4; ++c)
      lmax = fmaxf(lmax, negd3(cx, cy, cz, xs, ys, zs, s * 256 + c * 64 + lane));

  float sv = lmax;
  for (int k = 2; k <= 64; k <<= 1) {
    for (int j = k >> 1; j > 0; j >>= 1) {
      float ov = __shfl_xor(sv, j);
      bool up = ((lane & k) == 0);
      bool lower = ((lane & j) == 0);
      bool mineLess = sv < ov;
      bool keepMine = (up == lower) ? mineLess : !mineLess;
      sv = keepMine ? sv : ov;
    }
  }
  float T = __shfl(sv, 44);

  // pass 2: recompute + count
  int myCnt = 0;
#pragma unroll
  for (int s = 0; s < 16; ++s)
#pragma unroll
    for (int c = 0; c < 4; ++c)
      myCnt += (negd3(cx, cy, cz, xs, ys, zs, s * 256 + c * 64 + lane) >= T) ? 1 : 0;
  int ofs = myCnt;
  for (int dlt = 1; dlt < 64; dlt <<= 1) {
    int o = __shfl_up(ofs, dlt);
    if (lane >= dlt) ofs += o;
  }
  int total = __shfl(ofs, 63);
  ofs -= myCnt;

  // pass 3: recompute + write candidate indices (same lane-major order)
  int w = ofs;
#pragma unroll
  for (int s = 0; s < 16; ++s)
#pragma unroll
    for (int c = 0; c < 4; ++c) {
      int m = s * 256 + c * 64 + lane;
      if (negd3(cx, cy, cz, xs, ys, zs, m) >= T) {
        if (w < MAXCAND) scand[wave][w] = (u16)m;
        ++w;
      }
    }
  int cnt = imin(total, MAXCAND);
  int nch = (cnt + 63) >> 6;

  double runV = -__builtin_inf();
  int runI = 0x7fffffff;
  for (int ch = 0; ch < nch; ++ch) {
    int slot = ch * 64 + lane;
    int m = (slot < cnt) ? (int)scand[wave][slot] : -1;
    double val = -__builtin_inf();
    int vi = 0x7fffffff;
    if (m >= 0) {
      double dx = (double)cx - (double)xs[m];
      double dy = (double)cy - (double)ys[m];
      double dz = (double)cz - (double)zs[m];
      val = -(dx * dx + dy * dy + dz * dz);
      vi = m;
    }
    for (int k = 2; k <= 64; k <<= 1) {
      for (int j = k >> 1; j > 0; j >>= 1) {
        double ov = __shfl_xor(val, j);
        int oi = __shfl_xor(vi, j);
        bool up = ((lane & k) == 0);
        bool lower = ((lane & j) == 0);
        bool mineLess = comp_less(val, vi, ov, oi);
        bool keepMine = (up == lower) ? mineLess : !mineLess;
        if (!keepMine) { val = ov; vi = oi; }
      }
    }
    if (ch == 0) {
      runV = val;
      runI = vi;
    } else {
      double rv = __shfl(val, 63 - lane);
      int ri = __shfl(vi, 63 - lane);
      if (comp_less(runV, runI, rv, ri)) { runV = rv; runI = ri; }
      for (int j = 32; j > 0; j >>= 1) {
        double ov = __shfl_xor(runV, j);
        int oi = __shfl_xor(runI, j);
        bool lower = ((lane & j) == 0);
        bool mineLess = comp_less(runV, runI, ov, oi);
        bool keepMine = lower ? mineLess : !mineLess;
        if (!keepMine) { runV = ov; runI = oi; }
      }
    }
  }
  if (lane >= 44)
    idxout[((size_t)blockIdx.y * NPTS + row) * KNN + (63 - lane)] = runI;
}

// ---------------- gather-max + per-block fp64 BN partial stats ----------------
template <int NO>
__global__ __launch_bounds__(256) void gathermax_kernel(const float* __restrict__ PQ,
                                                        const int* __restrict__ idx,
                                                        float* __restrict__ hmax, int O,
                                                        double* __restrict__ pbuf) {
  __shared__ double sh1[4][256];
  __shared__ double sh2[4][256];
  int t = threadIdx.x;
  int wave = t >> 6, lane = t & 63;
  int pt = blockIdx.x * 4 + wave;
  int b = pt >> 12;
  int O2 = 2 * O;
  int iv = idx[(size_t)pt * KNN + (lane % KNN)];
  const float* Qp = PQ + (size_t)pt * O2 + O + lane * NO;
  float q[NO], mx[NO];
  double s1[NO], s2[NO];
#pragma unroll
  for (int c = 0; c < NO; ++c) {
    q[c] = Qp[c];
    mx[c] = -__builtin_inff();
    s1[c] = 0.0;
    s2[c] = 0.0;
  }
#pragma unroll
  for (int k = 0; k < KNN; ++k) {
    int m = __shfl(iv, k);
    const float* Pp = PQ + ((size_t)(b << 12) + m) * O2 + lane * NO;
    float p[NO];
#pragma unroll
    for (int c = 0; c < NO; ++c) p[c] = Pp[c];
#pragma unroll
    for (int c = 0; c < NO; ++c) {
      float h = p[c] + q[c];
      mx[c] = fmaxf(mx[c], h);
      double hd = (double)h;
      s1[c] += hd;
      s2[c] += hd * hd;
    }
  }
  float* Hp = hmax + (size_t)pt * O + lane * NO;
#pragma unroll
  for (int c = 0; c < NO; ++c) {
    Hp[c] = mx[c];
    sh1[wave][lane * NO + c] = s1[c];
    sh2[wave][lane * NO + c] = s2[c];
  }
  __syncthreads();
  if (t < O) {
    double a = 0.0, bb = 0.0;
#pragma unroll
    for (int w = 0; w < 4; ++w) {
      a += sh1[w][t];
      bb += sh2[w][t];
    }
    pbuf[(size_t)blockIdx.x * O2 + t] = a;
    pbuf[(size_t)blockIdx.x * O2 + O + t] = bb;
  }
}

// ---------------- deterministic parallel fp64 BN reduce + finalize ----------------
__global__ __launch_bounds__(256) void bn_reduce_finalize(const double* __restrict__ pbuf,
                                                          int nblk, int O,
                                                          const float* __restrict__ g,
                                                          const float* __restrict__ bb,
                                                          double invcount,
                                                          float* __restrict__ s_out,
                                                          float* __restrict__ t_out) {
  __shared__ double sh1[256];
  __shared__ double sh2[256];
  int o = blockIdx.x;
  int t = threadIdx.x;
  double s1 = 0.0, s2 = 0.0;
  for (int blk = t; blk < nblk; blk += 256) {
    s1 += pbuf[(size_t)blk * 2 * O + o];
    s2 += pbuf[(size_t)blk * 2 * O + O + o];
  }
  sh1[t] = s1;
  sh2[t] = s2;
  __syncthreads();
  for (int s = 128; s > 0; s >>= 1) {
    if (t < s) {
      sh1[t] += sh1[t + s];
      sh2[t] += sh2[t + s];
    }
    __syncthreads();
  }
  if (t == 0) {
    double mean = sh1[0] * invcount;
    double var = sh2[0] * invcount - mean * mean;
    double s = (double)g[o] / sqrt(var + BNEPS);
    s_out[o] = (float)s;
    t_out[o] = (float)((double)bb[o] - mean * s);
  }
}

// y = leaky(hmax*s+t) into feat column slice (fp32) + featbf (bf16, fused conversion)
__global__ void apply_kernel(const float* __restrict__ hmax, const float* __restrict__ s,
                             const float* __restrict__ tt, float* __restrict__ feat,
                             u16* __restrict__ featbf, int colOff, int logO, int total) {
  int i = blockIdx.x * 256 + threadIdx.x;
  if (i >= total) return;
  int O = 1 << logO;
  int o = i & (O - 1);
  int pp = i >> logO;
  float v = hmax[i] * s[o] + tt[o];
  float r = v > 0.f ? v : SLOPE * v;
  size_t di = (size_t)pp * 512 + colOff + o;
  feat[di] = r;
  featbf[di] = f2bf(r);
}

// out[b][o][n] = leaky(h5[b][n][o]*s+t)
__global__ void out_kernel(const float* __restrict__ h5, const float* __restrict__ s,
                           const float* __restrict__ tt, float* __restrict__ out) {
  __shared__ float tile[32][33];
  int b = blockIdx.z;
  int n0 = blockIdx.x * 32, o0 = blockIdx.y * 32;
  int t = threadIdx.x;
  for (int e = t; e < 1024; e += 256) {
    int rn = e >> 5, co = e & 31;
    int o = o0 + co;
    float v = h5[((size_t)b * NPTS + n0 + rn) * 1024 + o] * s[o] + tt[o];
    tile[rn][co] = v > 0.f ? v : SLOPE * v;
  }
  __syncthreads();
  for (int e = t; e < 1024; e += 256) {
    int ro = e >> 5, cn = e & 31;
    out[((size_t)b * 1024 + o0 + ro) * NPTS + n0 + cn] = tile[cn][ro];
  }
}

// ---------------- host ----------------
extern "C" void kernel_launch(void* const* d_in, const int* in_sizes, int n_in,
                              void* d_out, int out_size, void* d_ws, size_t ws_size,
                              hipStream_t stream) {
  const float* x = (const float*)d_in[0];
  const float* Wm[5] = {(const float*)d_in[1], (const float*)d_in[4], (const float*)d_in[7],
                        (const float*)d_in[10], (const float*)d_in[13]};
  const float* gv[5] = {(const float*)d_in[2], (const float*)d_in[5], (const float*)d_in[8],
                        (const float*)d_in[11], (const float*)d_in[14]};
  const float* bvv[5] = {(const float*)d_in[3], (const float*)d_in[6], (const float*)d_in[9],
                         (const float*)d_in[12], (const float*)d_in[15]};
  float* out = (float*)d_out;

  char* wsb = (char*)d_ws;
  size_t off = 0;
  auto alloc = [&](size_t bytes) -> char* {
    off = (off + 255) & ~(size_t)255;
    char* p = wsb + off;
    off += bytes;
    return p;
  };
  float* xb = (float*)alloc((size_t)BATCH * NPTS * 3 * 4);
  float* xxb = (float*)alloc((size_t)BATCH * NPTS * 4);
  int* idxb = (int*)alloc((size_t)BATCH * NPTS * KNN * 4);
  float* feat = (float*)alloc((size_t)BATCH * NPTS * 512 * 4);
  float* hmax = (float*)alloc((size_t)BATCH * NPTS * 256 * 4);
  float* h5 = (float*)alloc((size_t)BATCH * NPTS * 1024 * 4);
  float* PQ = h5;  // alias: PQ used per-layer, h5 only needed after
  float* U1 = (float*)alloc(3 * 128 * 4);
  float* U2 = (float*)alloc(64 * 128 * 4);
  float* U3 = (float*)alloc(64 * 256 * 4);
  float* U4 = (float*)alloc(128 * 512 * 4);
  u16* featbf = (u16*)alloc((size_t)BATCH * NPTS * 512 * 2);
  u16* w5bf = (u16*)alloc((size_t)1024 * 512 * 2);
  u16* xhi = (u16*)alloc((size_t)BATCH * NPTS * 128 * 2);
  u16* xlo = (u16*)alloc((size_t)BATCH * NPTS * 128 * 2);
  double* pbuf = (double*)alloc((size_t)2048 * 512 * 8);
  float* stv = (float*)alloc(3072 * 4);
  off = (off + 255) & ~(size_t)255;
  size_t avail = (ws_size > off) ? (ws_size - off) : 0;
  size_t slab = (size_t)NPTS * NPTS * 2;              // one batch's fp16 dist matrix
  int nbfit = (int)imin((int)(avail / slab), BATCH);  // 0, 1, or 2 slabs fit
  size_t rmax = avail / ((size_t)NPTS * 2);
  int R;
  if (rmax >= NPTS) R = NPTS;
  else {
    R = (int)(rmax & ~(size_t)127);
    if (R < 128) R = 128;
  }
  _Float16* distbuf = (_Float16*)(wsb + off);

  float* sv[5] = {stv + 0, stv + 128, stv + 256, stv + 512, stv + 1024};
  float* tv[5] = {stv + 64, stv + 192, stv + 384, stv + 768, stv + 2048};
  float* Us[4] = {U1, U2, U3, U4};
  const int Cs[4] = {3, 64, 64, 128};
  const int Osz[4] = {64, 64, 128, 256};
  const int ntile = (NPTS / 128) * (NPTS / 128 + 1) / 2;  // 528

  xtrans_kernel<<<(BATCH * 3 * NPTS + 255) / 256, 256, 0, stream>>>(x, xb);
  for (int l = 0; l < 4; ++l)
    uprep_kernel<<<(Cs[l] * Osz[l] + 255) / 256, 256, 0, stream>>>(Wm[l], Us[l], Osz[l], Cs[l]);
  tobf16_kernel<<<(1024 * 512 / 4 + 255) / 256, 256, 0, stream>>>(Wm[4], w5bf, 1024 * 512 / 4);

  auto knn = [&](const float* Xbase, int lda, int C) {
    xx_kernel<<<(BATCH * NPTS + 255) / 256, 256, 0, stream>>>(Xbase, lda, C, xxb);
    size_t selems = (size_t)NPTS * NPTS;
    if (nbfit >= 1) {
      int ngroups = BATCH * NPTS * (C / 4);
      tosplit_kernel<<<(ngroups + 255) / 256, 256, 0, stream>>>(Xbase, lda, C, xhi, xlo, ngroups);
    }
    if (nbfit >= BATCH) {
      dist_sym_mfma_kernel<<<dim3(ntile, BATCH), 256, 0, stream>>>(xhi, xlo, C, xxb, distbuf,
                                                                   selems);
      topk_fast_kernel<<<dim3(NPTS / 4, BATCH), 256, 0, stream>>>(
          distbuf, selems, Xbase, (size_t)NPTS * lda, lda, C, idxb, (size_t)NPTS * KNN, 0, NPTS);
    } else if (nbfit >= 1) {
      for (int b = 0; b < BATCH; ++b) {
        const float* Xb = Xbase + (size_t)b * NPTS * lda;
        dist_sym_mfma_kernel<<<dim3(ntile, 1), 256, 0, stream>>>(
            xhi + (size_t)b * NPTS * C, xlo + (size_t)b * NPTS * C, C, xxb + (size_t)b * NPTS,
            distbuf, 0);
        topk_fast_kernel<<<dim3(NPTS / 4, 1), 256, 0, stream>>>(
            distbuf, 0, Xb, 0, lda, C, idxb + (size_t)b * NPTS * KNN, 0, 0, NPTS);
      }
    } else {
      for (int b = 0; b < BATCH; ++b) {
        const float* Xb = Xbase + (size_t)b * NPTS * lda;
        for (int n0 = 0; n0 < NPTS; n0 += R) {
          int rows = imin(R, NPTS - n0);
          gemm128<true, true><<<dim3(NPTS / 128, rows / 128), 256, 0, stream>>>(
              Xb + (size_t)n0 * lda, lda, Xb, lda, (void*)distbuf, NPTS, C,
              xxb + (size_t)b * NPTS + n0, xxb + (size_t)b * NPTS);
          topk_fast_kernel<<<dim3(rows / 4, 1), 256, 0, stream>>>(
              distbuf, 0, Xb, 0, lda, C, idxb + (size_t)b * NPTS * KNN, 0, n0, rows);
        }
      }
    }
  };

  auto edge = [&](int li, const float* Xbase, int lda, int C, int O, int colOff) {
    if (li == 0) {
      dist3_topk_kernel<<<dim3(NPTS / 8, BATCH), 512, 0, stream>>>(Xbase, idxb);
    } else {
      knn(Xbase, lda, C);
    }
    int O2 = 2 * O;
    gemm128<false, false><<<dim3(O2 / 128, BATCH * NPTS / 128), 256, 0, stream>>>(
        Xbase, lda, Us[li], O2, (void*)PQ, O2, C, nullptr, nullptr);
    int nblk = BATCH * NPTS / 4;
    if (O == 64)
      gathermax_kernel<1><<<nblk, 256, 0, stream>>>(PQ, idxb, hmax, O, pbuf);
    else if (O == 128)
      gathermax_kernel<2><<<nblk, 256, 0, stream>>>(PQ, idxb, hmax, O, pbuf);
    else
      gathermax_kernel<4><<<nblk, 256, 0, stream>>>(PQ, idxb, hmax, O, pbuf);
    bn_reduce_finalize<<<O, 256, 0, stream>>>(pbuf, nblk, O, gv[li], bvv[li],
                                              1.0 / ((double)BATCH * NPTS * KNN), sv[li], tv[li]);
    int logO = (O == 64) ? 6 : (O == 128) ? 7 : 8;
    int total = BATCH * NPTS * O;
    apply_kernel<<<(total + 255) / 256, 256, 0, stream>>>(hmax, sv[li], tv[li], feat, featbf,
                                                          colOff, logO, total);
  };

  edge(0, xb, 3, 3, 64, 0);
  edge(1, feat, 512, 64, 64, 64);
  edge(2, feat + 64, 512, 64, 128, 128);
  edge(3, feat + 128, 512, 128, 256, 256);

  fc_mfma_kernel<<<dim3(1024 / 128, BATCH * NPTS / 128), 256, 0, stream>>>(featbf, w5bf, h5, pbuf);
  bn_reduce_finalize<<<1024, 256, 0, stream>>>(pbuf, 64, 1024, gv[4], bvv[4],
                                               1.0 / ((double)BATCH * NPTS), sv[4], tv[4]);
  out_kernel<<<dim3(NPTS / 32, 1024 / 32, BATCH), 256, 0, stream>>>(h5, sv[4], tv[4], out);
}

// Round 4
// 574.914 us; speedup vs baseline: 1.0433x; 1.0433x over previous
//
#include <hip/hip_runtime.h>
#include <cmath>

#define KNN 20
#define NPTS 4096
#define BATCH 2
#define SLOPE 0.2f
#define BNEPS 1e-5
#define GTK 16
#define MAXCAND 256

typedef unsigned short u16;
typedef __attribute__((ext_vector_type(8))) short bf16x8;
typedef __attribute__((ext_vector_type(4))) float f32x4;
typedef _Float16 h8 __attribute__((ext_vector_type(8)));
typedef _Float16 h4 __attribute__((ext_vector_type(4)));

static __device__ __host__ inline int imin(int a, int b) { return a < b ? a : b; }

__device__ inline u16 f2bf(float v) {
  unsigned x = __float_as_uint(v);
  unsigned rr = x + 0x7fff + ((x >> 16) & 1);
  return (u16)(rr >> 16);
}

// ---------------- utility kernels ----------------
// x (B,3,N) -> xb (B,N,3)
__global__ void xtrans_kernel(const float* __restrict__ x, float* __restrict__ xb) {
  int i = blockIdx.x * 256 + threadIdx.x;
  if (i < BATCH * 3 * NPTS) {
    int b = i / (3 * NPTS);
    int r = i - b * 3 * NPTS;
    int c = r / NPTS;
    int n = r - c * NPTS;
    xb[((size_t)b * NPTS + n) * 3 + c] = x[i];
  }
}

// W (O, 2C) -> U (C, 2O): U[j][o]=W[o][j]; U[j][O+o]=W[o][C+j]-W[o][j]
__global__ void uprep_kernel(const float* __restrict__ W, float* __restrict__ U, int O, int C) {
  int i = blockIdx.x * 256 + threadIdx.x;
  if (i < C * O) {
    int j = i / O, o = i - j * O;
    float w1 = W[(size_t)o * 2 * C + j];
    float w2 = W[(size_t)o * 2 * C + C + j];
    U[(size_t)j * 2 * O + o] = w1;
    U[(size_t)j * 2 * O + O + o] = w2 - w1;
  }
}

// squared norms per point (fp64 accumulate, fp32 store — candidate pass only)
__global__ void xx_kernel(const float* __restrict__ X, int stride, int C, float* __restrict__ xx) {
  int i = blockIdx.x * 256 + threadIdx.x;
  if (i < BATCH * NPTS) {
    const float* r = X + (size_t)i * stride;
    double s = 0.0;
    for (int c = 0; c < C; ++c) s += (double)r[c] * (double)r[c];
    xx[i] = (float)s;
  }
}

// fp32 -> bf16 (RNE), 4 elements/thread
__global__ void tobf16_kernel(const float* __restrict__ src, u16* __restrict__ dst, int n4) {
  int i = blockIdx.x * 256 + threadIdx.x;
  if (i < n4) {
    float4 v = *(const float4*)&src[(size_t)i * 4];
    unsigned o[4];
#pragma unroll
    for (int j = 0; j < 4; ++j) o[j] = f2bf(((const float*)&v)[j]);
    uint2 pk;
    pk.x = o[0] | (o[1] << 16);
    pk.y = o[2] | (o[3] << 16);
    *(uint2*)&dst[(size_t)i * 4] = pk;
  }
}

// fp32 X (row-major, lda) -> split hi/lo bf16 (row-major, C), 4 cols/thread
__global__ void tosplit_kernel(const float* __restrict__ X, int lda, int C,
                               u16* __restrict__ hi, u16* __restrict__ lo, int ngroups) {
  int g = blockIdx.x * 256 + threadIdx.x;
  if (g >= ngroups) return;
  int perRow = C >> 2;
  int r = g / perRow;
  int cq = (g - r * perRow) * 4;
  float4 v = *(const float4*)&X[(size_t)r * lda + cq];
  unsigned ho[4], lo_[4];
#pragma unroll
  for (int j = 0; j < 4; ++j) {
    float f = ((const float*)&v)[j];
    u16 h = f2bf(f);
    float hv = __uint_as_float(((unsigned)h) << 16);
    ho[j] = h;
    lo_[j] = f2bf(f - hv);
  }
  uint2 ph, pl;
  ph.x = ho[0] | (ho[1] << 16);
  ph.y = ho[2] | (ho[3] << 16);
  pl.x = lo_[0] | (lo_[1] << 16);
  pl.y = lo_[2] | (lo_[3] << 16);
  size_t di = (size_t)r * C + cq;
  *(uint2*)&hi[di] = ph;
  *(uint2*)&lo[di] = pl;
}

// ---------------- generic 128x128 fp32 GEMM, 8x8 micro (single-buffered) ----------------
// C[M x N] = A[M x K] * (BT ? B[N x K]^T : B[K x N]); DIST epilogue writes fp16.
template <bool BT, bool DIST>
__global__ __launch_bounds__(256) void gemm128(const float* __restrict__ A, int lda,
                                               const float* __restrict__ B, int ldb,
                                               void* __restrict__ Cout, int ldc, int K,
                                               const float* __restrict__ xxA,
                                               const float* __restrict__ xxB) {
  __shared__ __align__(16) float sA[GTK][144];
  __shared__ __align__(16) float sB[GTK][144];
  int t = threadIdx.x;
  int tx = t & 15, ty = t >> 4;
  int row0 = blockIdx.y * 128, col0 = blockIdx.x * 128;
  float acc[8][8] = {};

  for (int k0 = 0; k0 < K; k0 += GTK) {
    bool fast = (k0 + GTK <= K);
    if (fast) {
#pragma unroll
      for (int it = 0; it < 2; ++it) {
        int i = t + it * 256;
        int r = i >> 2, q = i & 3;
        const float4 av = *(const float4*)&A[(size_t)(row0 + r) * lda + k0 + q * 4];
        int pr = r + ((r >> 5) << 2);
        sA[q * 4 + 0][pr] = av.x;
        sA[q * 4 + 1][pr] = av.y;
        sA[q * 4 + 2][pr] = av.z;
        sA[q * 4 + 3][pr] = av.w;
      }
    } else {
#pragma unroll
      for (int it = 0; it < 2; ++it) {
        int i = t + it * 256;
        int r = i >> 2, q = i & 3;
        int pr = r + ((r >> 5) << 2);
#pragma unroll
        for (int j = 0; j < 4; ++j) {
          int k = q * 4 + j;
          sA[k][pr] = (k0 + k < K) ? A[(size_t)(row0 + r) * lda + k0 + k] : 0.f;
        }
      }
    }
    if (BT) {
      if (fast) {
#pragma unroll
        for (int it = 0; it < 2; ++it) {
          int i = t + it * 256;
          int r = i >> 2, q = i & 3;
          const float4 bv = *(const float4*)&B[(size_t)(col0 + r) * ldb + k0 + q * 4];
          int pr = r + ((r >> 5) << 2);
          sB[q * 4 + 0][pr] = bv.x;
          sB[q * 4 + 1][pr] = bv.y;
          sB[q * 4 + 2][pr] = bv.z;
          sB[q * 4 + 3][pr] = bv.w;
        }
      } else {
#pragma unroll
        for (int it = 0; it < 2; ++it) {
          int i = t + it * 256;
          int r = i >> 2, q = i & 3;
          int pr = r + ((r >> 5) << 2);
#pragma unroll
          for (int j = 0; j < 4; ++j) {
            int k = q * 4 + j;
            sB[k][pr] = (k0 + k < K) ? B[(size_t)(col0 + r) * ldb + k0 + k] : 0.f;
          }
        }
      }
    } else {
#pragma unroll
      for (int it = 0; it < 2; ++it) {
        int i = t + it * 256;
        int k = i >> 5, nq = (i & 31) * 4;
        int pc = nq + ((nq >> 5) << 2);
        float4 bv = make_float4(0.f, 0.f, 0.f, 0.f);
        if (k0 + k < K) bv = *(const float4*)&B[(size_t)(k0 + k) * ldb + col0 + nq];
        *(float4*)&sB[k][pc] = bv;
      }
    }
    __syncthreads();
    int prA = ty * 8 + ((ty >> 2) << 2);
    int prB = tx * 8 + ((tx >> 2) << 2);
#pragma unroll
    for (int kk = 0; kk < GTK; ++kk) {
      float a[8], b[8];
      *(float4*)&a[0] = *(const float4*)&sA[kk][prA];
      *(float4*)&a[4] = *(const float4*)&sA[kk][prA + 4];
      *(float4*)&b[0] = *(const float4*)&sB[kk][prB];
      *(float4*)&b[4] = *(const float4*)&sB[kk][prB + 4];
#pragma unroll
      for (int i = 0; i < 8; ++i)
#pragma unroll
        for (int j = 0; j < 8; ++j) acc[i][j] += a[i] * b[j];
    }
    __syncthreads();
  }

  if (DIST) {
    _Float16* Ch = (_Float16*)Cout;
#pragma unroll
    for (int i = 0; i < 8; ++i) {
      int gr = row0 + ty * 8 + i;
      float xa = xxA[gr];
      h8 o;
#pragma unroll
      for (int j = 0; j < 8; ++j) {
        int gc = col0 + tx * 8 + j;
        o[j] = (_Float16)(2.f * acc[i][j] - xa - xxB[gc]);
      }
      *(h8*)&Ch[(size_t)gr * ldc + col0 + tx * 8] = o;
    }
  } else {
    float* Cf = (float*)Cout;
#pragma unroll
    for (int i = 0; i < 8; ++i) {
      int gr = row0 + ty * 8 + i;
#pragma unroll
      for (int jq = 0; jq < 2; ++jq) {
        float4 o;
#pragma unroll
        for (int j = 0; j < 4; ++j) ((float*)&o)[j] = acc[i][jq * 4 + j];
        *(float4*)&Cf[(size_t)gr * ldc + col0 + tx * 8 + jq * 4] = o;
      }
    }
  }
}

// ---------------- split-bf16 MFMA symmetric dist: lower-triangle tiles, mirrored write ----
// <x,y> = hi.hi + hi.lo + lo.hi (3 chained bf16 MFMAs, fp32 acc; lo.lo term ~2^-16 dropped).
// Epilogue: fp16 tile in LDS (rows padded to 136 u16), coalesced h8 writes both orientations.
// grid (ntile, nbatch). Fragment maps identical to fc_mfma (m89-verified).
// LDS layout: 4 slabs of 5120 u16 at offsets a*5120 (Ahi, Alo, Bhi, Blo), rows of 40 u16.
__global__ __launch_bounds__(256) void dist_sym_mfma_kernel(const u16* __restrict__ Xhi,
                                                            const u16* __restrict__ Xlo, int K,
                                                            const float* __restrict__ xx,
                                                            _Float16* __restrict__ dist,
                                                            size_t dstride) {
  __shared__ __align__(16) u16 smem[20544];  // staging 4x128x40 (40960 B) / tile 128x136 (34816 B)
  int t = threadIdx.x;
  int lane = t & 63, wave = t >> 6;
  const u16* xh = Xhi + (size_t)blockIdx.y * NPTS * K;
  const u16* xl = Xlo + (size_t)blockIdx.y * NPTS * K;
  const float* xxv = xx + (size_t)blockIdx.y * NPTS;
  _Float16* db = dist + (size_t)blockIdx.y * dstride;
  int l = blockIdx.x;
  int bi = (int)((sqrtf(8.f * (float)l + 1.f) - 1.f) * 0.5f);
  while ((bi + 1) * (bi + 2) / 2 <= l) ++bi;
  while (bi * (bi + 1) / 2 > l) --bi;
  int bj = l - bi * (bi + 1) / 2;
  int row0 = bi * 128, col0 = bj * 128;
  int wr = (wave >> 1) * 64, wc = (wave & 1) * 64;
  int m = lane & 15, q = lane >> 4;
  f32x4 acc[4][4];
#pragma unroll
  for (int i = 0; i < 4; ++i)
#pragma unroll
    for (int j = 0; j < 4; ++j) acc[i][j] = (f32x4){0.f, 0.f, 0.f, 0.f};

  for (int k0 = 0; k0 < K; k0 += 32) {
#pragma unroll
    for (int it = 0; it < 8; ++it) {
      int e = t + it * 256;
      int a = e >> 9, idx = e & 511;
      int r = idx >> 2, qq = idx & 3;
      const u16* src = (a == 0 || a == 2) ? xh : xl;
      int base = (a < 2) ? row0 : col0;
      *(uint4*)&smem[a * 5120 + r * 40 + qq * 8] =
          *(const uint4*)&src[(size_t)(base + r) * K + k0 + qq * 8];
    }
    __syncthreads();
    bf16x8 ah[4], al[4], bh[4], bl[4];
#pragma unroll
    for (int i = 0; i < 4; ++i) {
      ah[i] = *(const bf16x8*)&smem[0 * 5120 + (wr + i * 16 + m) * 40 + q * 8];
      al[i] = *(const bf16x8*)&smem[1 * 5120 + (wr + i * 16 + m) * 40 + q * 8];
    }
#pragma unroll
    for (int j = 0; j < 4; ++j) {
      bh[j] = *(const bf16x8*)&smem[2 * 5120 + (wc + j * 16 + m) * 40 + q * 8];
      bl[j] = *(const bf16x8*)&smem[3 * 5120 + (wc + j * 16 + m) * 40 + q * 8];
    }
#pragma unroll
    for (int i = 0; i < 4; ++i)
#pragma unroll
      for (int j = 0; j < 4; ++j) {
        acc[i][j] = __builtin_amdgcn_mfma_f32_16x16x32_bf16(ah[i], bh[j], acc[i][j], 0, 0, 0);
        acc[i][j] = __builtin_amdgcn_mfma_f32_16x16x32_bf16(ah[i], bl[j], acc[i][j], 0, 0, 0);
        acc[i][j] = __builtin_amdgcn_mfma_f32_16x16x32_bf16(al[i], bh[j], acc[i][j], 0, 0, 0);
      }
    __syncthreads();
  }

  // DIST transform -> fp16 LDS tile (reuses staging smem; all reads drained by loop-end sync)
  _Float16* tile = (_Float16*)smem;
  {
    float xbv[4];
#pragma unroll
    for (int j = 0; j < 4; ++j) xbv[j] = xxv[col0 + wc + j * 16 + m];
#pragma unroll
    for (int i = 0; i < 4; ++i)
#pragma unroll
      for (int reg = 0; reg < 4; ++reg) {
        int r = wr + i * 16 + q * 4 + reg;
        float xa = xxv[row0 + r];
#pragma unroll
        for (int j = 0; j < 4; ++j)
          tile[r * 136 + wc + j * 16 + m] = (_Float16)(2.f * acc[i][j][reg] - xa - xbv[j]);
      }
  }
  __syncthreads();
  // direct tile (row0, col0): coalesced h8 per 8-col segment
  for (int e = t; e < 2048; e += 256) {
    int r = e >> 4, seg = e & 15;
    *(h8*)&db[(size_t)(row0 + r) * NPTS + col0 + seg * 8] = *(const h8*)&tile[r * 136 + seg * 8];
  }
  // mirrored tile (col0, row0): transposed LDS reads, coalesced global h8 writes
  if (bi != bj) {
    for (int e = t; e < 2048; e += 256) {
      int c = e >> 4, seg = e & 15;
      h8 o;
#pragma unroll
      for (int i = 0; i < 8; ++i) o[i] = tile[(seg * 8 + i) * 136 + c];
      *(h8*)&db[(size_t)(col0 + c) * NPTS + row0 + seg * 8] = o;
    }
  }
}

// ---------------- bf16 MFMA FC: C[8192x1024] = A[8192x512] * B[1024x512]^T ----------------
// Epilogue additionally emits per-block fp64 column sum/sumsq partials (replaces colstats):
// block (cx,ry) owns rows [ry*128,+128) x cols [cx*128,+128); writes pbuf[ry*2048 + col] (sum)
// and pbuf[ry*2048 + 1024 + col] (sumsq) — same layout bn_reduce_finalize(nblk=64) consumes.
__global__ __launch_bounds__(256) void fc_mfma_kernel(const u16* __restrict__ A,
                                                      const u16* __restrict__ B,
                                                      float* __restrict__ C,
                                                      double* __restrict__ pbuf) {
  __shared__ u16 sA[128][56];
  __shared__ u16 sB[128][56];
  __shared__ double sred1[4][64];
  __shared__ double sred2[4][64];
  int t = threadIdx.x;
  int lane = t & 63, wave = t >> 6;
  int row0 = blockIdx.y * 128, col0 = blockIdx.x * 128;
  int wr = (wave >> 1) * 64, wc = (wave & 1) * 64;
  int m = lane & 15, q = lane >> 4;
  f32x4 acc[4][4];
#pragma unroll
  for (int i = 0; i < 4; ++i)
#pragma unroll
    for (int j = 0; j < 4; ++j) acc[i][j] = (f32x4){0.f, 0.f, 0.f, 0.f};
  for (int k0 = 0; k0 < 512; k0 += 32) {
#pragma unroll
    for (int it = 0; it < 2; ++it) {
      int i = t + it * 256;
      int r = i >> 2, ch = (i & 3) * 8;
      *(uint4*)&sA[r][ch] = *(const uint4*)&A[(size_t)(row0 + r) * 512 + k0 + ch];
      *(uint4*)&sB[r][ch] = *(const uint4*)&B[(size_t)(col0 + r) * 512 + k0 + ch];
    }
    __syncthreads();
    bf16x8 af[4], bf[4];
#pragma unroll
    for (int i = 0; i < 4; ++i) af[i] = *(const bf16x8*)&sA[wr + i * 16 + m][q * 8];
#pragma unroll
    for (int j = 0; j < 4; ++j) bf[j] = *(const bf16x8*)&sB[wc + j * 16 + m][q * 8];
#pragma unroll
    for (int i = 0; i < 4; ++i)
#pragma unroll
      for (int j = 0; j < 4; ++j)
        acc[i][j] = __builtin_amdgcn_mfma_f32_16x16x32_bf16(af[i], bf[j], acc[i][j], 0, 0, 0);
    __syncthreads();
  }
#pragma unroll
  for (int i = 0; i < 4; ++i)
#pragma unroll
    for (int j = 0; j < 4; ++j)
#pragma unroll
      for (int reg = 0; reg < 4; ++reg)
        C[(size_t)(row0 + wr + i * 16 + q * 4 + reg) * 1024 + col0 + wc + j * 16 + m] =
            acc[i][j][reg];

  // ---- fused column stats (fp64): per-thread 16 rows, q-group shuffle, wave-pair combine ----
#pragma unroll
  for (int j = 0; j < 4; ++j) {
    double s1 = 0.0, s2 = 0.0;
#pragma unroll
    for (int i = 0; i < 4; ++i)
#pragma unroll
      for (int reg = 0; reg < 4; ++reg) {
        double v = (double)acc[i][j][reg];
        s1 += v;
        s2 += v * v;
      }
    // reduce across q (lanes q*16+m, q=0..3): xor 16 then 32 keeps m fixed
    s1 += __shfl_xor(s1, 16);
    s2 += __shfl_xor(s2, 16);
    s1 += __shfl_xor(s1, 32);
    s2 += __shfl_xor(s2, 32);
    if (q == 0) {
      sred1[wave][j * 16 + m] = s1;
      sred2[wave][j * 16 + m] = s2;
    }
  }
  __syncthreads();
  if (t < 128) {
    int p = t >> 6, u = t & 63;  // p: wc half (waves p and p+2), u = j*16+m
    double a = sred1[p][u] + sred1[p + 2][u];
    double b = sred2[p][u] + sred2[p + 2][u];
    int gcol = col0 + p * 64 + u;
    pbuf[(size_t)blockIdx.y * 2048 + gcol] = a;
    pbuf[(size_t)blockIdx.y * 2048 + 1024 + gcol] = b;
  }
}

// ---------------- shared top-k selection helpers ----------------
__device__ inline bool comp_less(double v, int i, double ov, int oi) {
  return (v < ov) || (v == ov && i > oi);
}

// ---------------- fast top-k: threshold filter (fp16 dist) + fp64 rescore + bitonic sort ---
__global__ __launch_bounds__(256) void topk_fast_kernel(const _Float16* __restrict__ dist,
                                                        size_t dstride,
                                                        const float* __restrict__ Xb,
                                                        size_t xstride, int lda, int C,
                                                        int* __restrict__ idxout, size_t istride,
                                                        int n0, int rows) {
  __shared__ int scand[4][MAXCAND];
  int wave = threadIdx.x >> 6, lane = threadIdx.x & 63;
  int row = blockIdx.x * 4 + wave;
  if (row >= rows) return;
  const _Float16* distb = dist + (size_t)blockIdx.y * dstride;
  const float* Xbb = Xb + (size_t)blockIdx.y * xstride;
  int* idxb = idxout + (size_t)blockIdx.y * istride;
  const _Float16* d = distb + (size_t)row * NPTS;
  float v[16][4];
  float lmax = -__builtin_inff();
#pragma unroll
  for (int s = 0; s < 16; ++s) {
    h4 hv = *(const h4*)&d[s * 256 + lane * 4];
#pragma unroll
    for (int c = 0; c < 4; ++c) {
      v[s][c] = (float)hv[c];
      lmax = fmaxf(lmax, v[s][c]);
    }
  }

  float sv = lmax;
  for (int k = 2; k <= 64; k <<= 1) {
    for (int j = k >> 1; j > 0; j >>= 1) {
      float ov = __shfl_xor(sv, j);
      bool up = ((lane & k) == 0);
      bool lower = ((lane & j) == 0);
      bool mineLess = sv < ov;
      bool keepMine = (up == lower) ? mineLess : !mineLess;
      sv = keepMine ? sv : ov;
    }
  }
  float T = __shfl(sv, 44);

  int myCnt = 0;
#pragma unroll
  for (int s = 0; s < 16; ++s)
#pragma unroll
    for (int c = 0; c < 4; ++c) myCnt += (v[s][c] >= T) ? 1 : 0;
  int ofs = myCnt;
  for (int dlt = 1; dlt < 64; dlt <<= 1) {
    int o = __shfl_up(ofs, dlt);
    if (lane >= dlt) ofs += o;
  }
  int total = __shfl(ofs, 63);
  ofs -= myCnt;
  int w = ofs;
#pragma unroll
  for (int s = 0; s < 16; ++s)
#pragma unroll
    for (int c = 0; c < 4; ++c) {
      if (v[s][c] >= T) {
        if (w < MAXCAND) scand[wave][w] = s * 256 + lane * 4 + c;
        ++w;
      }
    }
  int cnt = imin(total, MAXCAND);
  int gn = n0 + row;
  const float* crow = Xbb + (size_t)gn * lda;
  int nch = (cnt + 63) >> 6;

  double runV = -__builtin_inf();
  int runI = 0x7fffffff;
  for (int ch = 0; ch < nch; ++ch) {
    int slot = ch * 64 + lane;
    int m = (slot < cnt) ? scand[wave][slot] : -1;
    double val = -__builtin_inf();
    int vi = 0x7fffffff;
    if (m >= 0) {
      const float* mrow = Xbb + (size_t)m * lda;
      double dd = 0.0;
      for (int c = 0; c < C; c += 4) {
        float4 a = *(const float4*)&crow[c];
        float4 b = *(const float4*)&mrow[c];
#pragma unroll
        for (int qq = 0; qq < 4; ++qq) {
          double df = (double)((const float*)&a)[qq] - (double)((const float*)&b)[qq];
          dd = fma(df, df, dd);
        }
      }
      val = -dd;
      vi = m;
    }
    for (int k = 2; k <= 64; k <<= 1) {
      for (int j = k >> 1; j > 0; j >>= 1) {
        double ov = __shfl_xor(val, j);
        int oi = __shfl_xor(vi, j);
        bool up = ((lane & k) == 0);
        bool lower = ((lane & j) == 0);
        bool mineLess = comp_less(val, vi, ov, oi);
        bool keepMine = (up == lower) ? mineLess : !mineLess;
        if (!keepMine) { val = ov; vi = oi; }
      }
    }
    if (ch == 0) {
      runV = val;
      runI = vi;
    } else {
      double rv = __shfl(val, 63 - lane);
      int ri = __shfl(vi, 63 - lane);
      if (comp_less(runV, runI, rv, ri)) { runV = rv; runI = ri; }
      for (int j = 32; j > 0; j >>= 1) {
        double ov = __shfl_xor(runV, j);
        int oi = __shfl_xor(runI, j);
        bool lower = ((lane & j) == 0);
        bool mineLess = comp_less(runV, runI, ov, oi);
        bool keepMine = lower ? mineLess : !mineLess;
        if (!keepMine) { runV = ov; runI = oi; }
      }
    }
  }
  if (lane >= 44) idxb[(size_t)gn * KNN + (63 - lane)] = runI;
}

// ---------------- fused layer-1 kNN (C=3): whole point set in LDS ----------------
// 512 threads = 8 waves/block, 8 rows/block, register-cached v[16][4] per wave
// (~88 VGPR -> 4 waves/SIMD band). LDS = 48K xyz + 4K u16 scand = 52K -> 2-3 blocks/CU,
// 16 waves/CU (VGPR-capped). This is the round-2 body (best measured: ~43 µs);
// round-3's recompute variant regressed (VGPR 108, +2x VALU). NO min-waves bound
// (forcing 8/EU clamps VGPR to 32 -> 600 MB/dispatch scratch spill).
__global__ __launch_bounds__(512) void dist3_topk_kernel(const float* __restrict__ Xb,
                                                         int* __restrict__ idxout) {
  __shared__ float xs[NPTS], ys[NPTS], zs[NPTS];
  __shared__ u16 scand[8][MAXCAND];
  int t = threadIdx.x;
  const float* Xbb = Xb + (size_t)blockIdx.y * NPTS * 3;
  for (int i = t; i < NPTS * 3; i += 512) {
    int n = i / 3, c = i - n * 3;
    float v = Xbb[i];
    if (c == 0) xs[n] = v;
    else if (c == 1) ys[n] = v;
    else zs[n] = v;
  }
  __syncthreads();
  int wave = t >> 6, lane = t & 63;
  int row = blockIdx.x * 8 + wave;
  float cx = xs[row], cy = ys[row], cz = zs[row];
  float v[16][4];
  float lmax = -__builtin_inff();
#pragma unroll
  for (int s = 0; s < 16; ++s)
#pragma unroll
    for (int c = 0; c < 4; ++c) {
      int m = s * 256 + c * 64 + lane;
      float dx = cx - xs[m], dy = cy - ys[m], dz = cz - zs[m];
      float dv = -(dx * dx + dy * dy + dz * dz);
      v[s][c] = dv;
      lmax = fmaxf(lmax, dv);
    }

  float sv = lmax;
  for (int k = 2; k <= 64; k <<= 1) {
    for (int j = k >> 1; j > 0; j >>= 1) {
      float ov = __shfl_xor(sv, j);
      bool up = ((lane & k) == 0);
      bool lower = ((lane & j) == 0);
      bool mineLess = sv < ov;
      bool keepMine = (up == lower) ? mineLess : !mineLess;
      sv = keepMine ? sv : ov;
    }
  }
  float T = __shfl(sv, 44);

  int myCnt = 0;
#pragma unroll
  for (int s = 0; s < 16; ++s)
#pragma unroll
    for (int c = 0; c < 4; ++c) myCnt += (v[s][c] >= T) ? 1 : 0;
  int ofs = myCnt;
  for (int dlt = 1; dlt < 64; dlt <<= 1) {
    int o = __shfl_up(ofs, dlt);
    if (lane >= dlt) ofs += o;
  }
  int total = __shfl(ofs, 63);
  ofs -= myCnt;
  int w = ofs;
#pragma unroll
  for (int s = 0; s < 16; ++s)
#pragma unroll
    for (int c = 0; c < 4; ++c) {
      if (v[s][c] >= T) {
        if (w < MAXCAND) scand[wave][w] = (u16)(s * 256 + c * 64 + lane);
        ++w;
      }
    }
  int cnt = imin(total, MAXCAND);
  int nch = (cnt + 63) >> 6;

  double runV = -__builtin_inf();
  int runI = 0x7fffffff;
  for (int ch = 0; ch < nch; ++ch) {
    int slot = ch * 64 + lane;
    int m = (slot < cnt) ? (int)scand[wave][slot] : -1;
    double val = -__builtin_inf();
    int vi = 0x7fffffff;
    if (m >= 0) {
      double dx = (double)cx - (double)xs[m];
      double dy = (double)cy - (double)ys[m];
      double dz = (double)cz - (double)zs[m];
      val = -(dx * dx + dy * dy + dz * dz);
      vi = m;
    }
    for (int k = 2; k <= 64; k <<= 1) {
      for (int j = k >> 1; j > 0; j >>= 1) {
        double ov = __shfl_xor(val, j);
        int oi = __shfl_xor(vi, j);
        bool up = ((lane & k) == 0);
        bool lower = ((lane & j) == 0);
        bool mineLess = comp_less(val, vi, ov, oi);
        bool keepMine = (up == lower) ? mineLess : !mineLess;
        if (!keepMine) { val = ov; vi = oi; }
      }
    }
    if (ch == 0) {
      runV = val;
      runI = vi;
    } else {
      double rv = __shfl(val, 63 - lane);
      int ri = __shfl(vi, 63 - lane);
      if (comp_less(runV, runI, rv, ri)) { runV = rv; runI = ri; }
      for (int j = 32; j > 0; j >>= 1) {
        double ov = __shfl_xor(runV, j);
        int oi = __shfl_xor(runI, j);
        bool lower = ((lane & j) == 0);
        bool mineLess = comp_less(runV, runI, ov, oi);
        bool keepMine = lower ? mineLess : !mineLess;
        if (!keepMine) { runV = ov; runI = oi; }
      }
    }
  }
  if (lane >= 44)
    idxout[((size_t)blockIdx.y * NPTS + row) * KNN + (63 - lane)] = runI;
}

// ---------------- gather-max + per-block fp64 BN partial stats ----------------
template <int NO>
__global__ __launch_bounds__(256) void gathermax_kernel(const float* __restrict__ PQ,
                                                        const int* __restrict__ idx,
                                                        float* __restrict__ hmax, int O,
                                                        double* __restrict__ pbuf) {
  __shared__ double sh1[4][256];
  __shared__ double sh2[4][256];
  int t = threadIdx.x;
  int wave = t >> 6, lane = t & 63;
  int pt = blockIdx.x * 4 + wave;
  int b = pt >> 12;
  int O2 = 2 * O;
  int iv = idx[(size_t)pt * KNN + (lane % KNN)];
  const float* Qp = PQ + (size_t)pt * O2 + O + lane * NO;
  float q[NO], mx[NO];
  double s1[NO], s2[NO];
#pragma unroll
  for (int c = 0; c < NO; ++c) {
    q[c] = Qp[c];
    mx[c] = -__builtin_inff();
    s1[c] = 0.0;
    s2[c] = 0.0;
  }
#pragma unroll
  for (int k = 0; k < KNN; ++k) {
    int m = __shfl(iv, k);
    const float* Pp = PQ + ((size_t)(b << 12) + m) * O2 + lane * NO;
    float p[NO];
#pragma unroll
    for (int c = 0; c < NO; ++c) p[c] = Pp[c];
#pragma unroll
    for (int c = 0; c < NO; ++c) {
      float h = p[c] + q[c];
      mx[c] = fmaxf(mx[c], h);
      double hd = (double)h;
      s1[c] += hd;
      s2[c] += hd * hd;
    }
  }
  float* Hp = hmax + (size_t)pt * O + lane * NO;
#pragma unroll
  for (int c = 0; c < NO; ++c) {
    Hp[c] = mx[c];
    sh1[wave][lane * NO + c] = s1[c];
    sh2[wave][lane * NO + c] = s2[c];
  }
  __syncthreads();
  if (t < O) {
    double a = 0.0, bb = 0.0;
#pragma unroll
    for (int w = 0; w < 4; ++w) {
      a += sh1[w][t];
      bb += sh2[w][t];
    }
    pbuf[(size_t)blockIdx.x * O2 + t] = a;
    pbuf[(size_t)blockIdx.x * O2 + O + t] = bb;
  }
}

// ---------------- deterministic parallel fp64 BN reduce + finalize ----------------
__global__ __launch_bounds__(256) void bn_reduce_finalize(const double* __restrict__ pbuf,
                                                          int nblk, int O,
                                                          const float* __restrict__ g,
                                                          const float* __restrict__ bb,
                                                          double invcount,
                                                          float* __restrict__ s_out,
                                                          float* __restrict__ t_out) {
  __shared__ double sh1[256];
  __shared__ double sh2[256];
  int o = blockIdx.x;
  int t = threadIdx.x;
  double s1 = 0.0, s2 = 0.0;
  for (int blk = t; blk < nblk; blk += 256) {
    s1 += pbuf[(size_t)blk * 2 * O + o];
    s2 += pbuf[(size_t)blk * 2 * O + O + o];
  }
  sh1[t] = s1;
  sh2[t] = s2;
  __syncthreads();
  for (int s = 128; s > 0; s >>= 1) {
    if (t < s) {
      sh1[t] += sh1[t + s];
      sh2[t] += sh2[t + s];
    }
    __syncthreads();
  }
  if (t == 0) {
    double mean = sh1[0] * invcount;
    double var = sh2[0] * invcount - mean * mean;
    double s = (double)g[o] / sqrt(var + BNEPS);
    s_out[o] = (float)s;
    t_out[o] = (float)((double)bb[o] - mean * s);
  }
}

// y = leaky(hmax*s+t) into feat column slice (fp32) + featbf (bf16, fused conversion)
__global__ void apply_kernel(const float* __restrict__ hmax, const float* __restrict__ s,
                             const float* __restrict__ tt, float* __restrict__ feat,
                             u16* __restrict__ featbf, int colOff, int logO, int total) {
  int i = blockIdx.x * 256 + threadIdx.x;
  if (i >= total) return;
  int O = 1 << logO;
  int o = i & (O - 1);
  int pp = i >> logO;
  float v = hmax[i] * s[o] + tt[o];
  float r = v > 0.f ? v : SLOPE * v;
  size_t di = (size_t)pp * 512 + colOff + o;
  feat[di] = r;
  featbf[di] = f2bf(r);
}

// out[b][o][n] = leaky(h5[b][n][o]*s+t)
__global__ void out_kernel(const float* __restrict__ h5, const float* __restrict__ s,
                           const float* __restrict__ tt, float* __restrict__ out) {
  __shared__ float tile[32][33];
  int b = blockIdx.z;
  int n0 = blockIdx.x * 32, o0 = blockIdx.y * 32;
  int t = threadIdx.x;
  for (int e = t; e < 1024; e += 256) {
    int rn = e >> 5, co = e & 31;
    int o = o0 + co;
    float v = h5[((size_t)b * NPTS + n0 + rn) * 1024 + o] * s[o] + tt[o];
    tile[rn][co] = v > 0.f ? v : SLOPE * v;
  }
  __syncthreads();
  for (int e = t; e < 1024; e += 256) {
    int ro = e >> 5, cn = e & 31;
    out[((size_t)b * 1024 + o0 + ro) * NPTS + n0 + cn] = tile[cn][ro];
  }
}

// ---------------- host ----------------
extern "C" void kernel_launch(void* const* d_in, const int* in_sizes, int n_in,
                              void* d_out, int out_size, void* d_ws, size_t ws_size,
                              hipStream_t stream) {
  const float* x = (const float*)d_in[0];
  const float* Wm[5] = {(const float*)d_in[1], (const float*)d_in[4], (const float*)d_in[7],
                        (const float*)d_in[10], (const float*)d_in[13]};
  const float* gv[5] = {(const float*)d_in[2], (const float*)d_in[5], (const float*)d_in[8],
                        (const float*)d_in[11], (const float*)d_in[14]};
  const float* bvv[5] = {(const float*)d_in[3], (const float*)d_in[6], (const float*)d_in[9],
                         (const float*)d_in[12], (const float*)d_in[15]};
  float* out = (float*)d_out;

  char* wsb = (char*)d_ws;
  size_t off = 0;
  auto alloc = [&](size_t bytes) -> char* {
    off = (off + 255) & ~(size_t)255;
    char* p = wsb + off;
    off += bytes;
    return p;
  };
  float* xb = (float*)alloc((size_t)BATCH * NPTS * 3 * 4);
  float* xxb = (float*)alloc((size_t)BATCH * NPTS * 4);
  int* idxb = (int*)alloc((size_t)BATCH * NPTS * KNN * 4);
  float* feat = (float*)alloc((size_t)BATCH * NPTS * 512 * 4);
  float* hmax = (float*)alloc((size_t)BATCH * NPTS * 256 * 4);
  float* h5 = (float*)alloc((size_t)BATCH * NPTS * 1024 * 4);
  float* PQ = h5;  // alias: PQ used per-layer, h5 only needed after
  float* U1 = (float*)alloc(3 * 128 * 4);
  float* U2 = (float*)alloc(64 * 128 * 4);
  float* U3 = (float*)alloc(64 * 256 * 4);
  float* U4 = (float*)alloc(128 * 512 * 4);
  u16* featbf = (u16*)alloc((size_t)BATCH * NPTS * 512 * 2);
  u16* w5bf = (u16*)alloc((size_t)1024 * 512 * 2);
  u16* xhi = (u16*)alloc((size_t)BATCH * NPTS * 128 * 2);
  u16* xlo = (u16*)alloc((size_t)BATCH * NPTS * 128 * 2);
  double* pbuf = (double*)alloc((size_t)2048 * 512 * 8);
  float* stv = (float*)alloc(3072 * 4);
  off = (off + 255) & ~(size_t)255;
  size_t avail = (ws_size > off) ? (ws_size - off) : 0;
  size_t slab = (size_t)NPTS * NPTS * 2;              // one batch's fp16 dist matrix
  int nbfit = (int)imin((int)(avail / slab), BATCH);  // 0, 1, or 2 slabs fit
  size_t rmax = avail / ((size_t)NPTS * 2);
  int R;
  if (rmax >= NPTS) R = NPTS;
  else {
    R = (int)(rmax & ~(size_t)127);
    if (R < 128) R = 128;
  }
  _Float16* distbuf = (_Float16*)(wsb + off);

  float* sv[5] = {stv + 0, stv + 128, stv + 256, stv + 512, stv + 1024};
  float* tv[5] = {stv + 64, stv + 192, stv + 384, stv + 768, stv + 2048};
  float* Us[4] = {U1, U2, U3, U4};
  const int Cs[4] = {3, 64, 64, 128};
  const int Osz[4] = {64, 64, 128, 256};
  const int ntile = (NPTS / 128) * (NPTS / 128 + 1) / 2;  // 528

  xtrans_kernel<<<(BATCH * 3 * NPTS + 255) / 256, 256, 0, stream>>>(x, xb);
  for (int l = 0; l < 4; ++l)
    uprep_kernel<<<(Cs[l] * Osz[l] + 255) / 256, 256, 0, stream>>>(Wm[l], Us[l], Osz[l], Cs[l]);
  tobf16_kernel<<<(1024 * 512 / 4 + 255) / 256, 256, 0, stream>>>(Wm[4], w5bf, 1024 * 512 / 4);

  auto knn = [&](const float* Xbase, int lda, int C) {
    xx_kernel<<<(BATCH * NPTS + 255) / 256, 256, 0, stream>>>(Xbase, lda, C, xxb);
    size_t selems = (size_t)NPTS * NPTS;
    if (nbfit >= 1) {
      int ngroups = BATCH * NPTS * (C / 4);
      tosplit_kernel<<<(ngroups + 255) / 256, 256, 0, stream>>>(Xbase, lda, C, xhi, xlo, ngroups);
    }
    if (nbfit >= BATCH) {
      dist_sym_mfma_kernel<<<dim3(ntile, BATCH), 256, 0, stream>>>(xhi, xlo, C, xxb, distbuf,
                                                                   selems);
      topk_fast_kernel<<<dim3(NPTS / 4, BATCH), 256, 0, stream>>>(
          distbuf, selems, Xbase, (size_t)NPTS * lda, lda, C, idxb, (size_t)NPTS * KNN, 0, NPTS);
    } else if (nbfit >= 1) {
      for (int b = 0; b < BATCH; ++b) {
        const float* Xb = Xbase + (size_t)b * NPTS * lda;
        dist_sym_mfma_kernel<<<dim3(ntile, 1), 256, 0, stream>>>(
            xhi + (size_t)b * NPTS * C, xlo + (size_t)b * NPTS * C, C, xxb + (size_t)b * NPTS,
            distbuf, 0);
        topk_fast_kernel<<<dim3(NPTS / 4, 1), 256, 0, stream>>>(
            distbuf, 0, Xb, 0, lda, C, idxb + (size_t)b * NPTS * KNN, 0, 0, NPTS);
      }
    } else {
      for (int b = 0; b < BATCH; ++b) {
        const float* Xb = Xbase + (size_t)b * NPTS * lda;
        for (int n0 = 0; n0 < NPTS; n0 += R) {
          int rows = imin(R, NPTS - n0);
          gemm128<true, true><<<dim3(NPTS / 128, rows / 128), 256, 0, stream>>>(
              Xb + (size_t)n0 * lda, lda, Xb, lda, (void*)distbuf, NPTS, C,
              xxb + (size_t)b * NPTS + n0, xxb + (size_t)b * NPTS);
          topk_fast_kernel<<<dim3(rows / 4, 1), 256, 0, stream>>>(
              distbuf, 0, Xb, 0, lda, C, idxb + (size_t)b * NPTS * KNN, 0, n0, rows);
        }
      }
    }
  };

  auto edge = [&](int li, const float* Xbase, int lda, int C, int O, int colOff) {
    if (li == 0) {
      dist3_topk_kernel<<<dim3(NPTS / 8, BATCH), 512, 0, stream>>>(Xbase, idxb);
    } else {
      knn(Xbase, lda, C);
    }
    int O2 = 2 * O;
    gemm128<false, false><<<dim3(O2 / 128, BATCH * NPTS / 128), 256, 0, stream>>>(
        Xbase, lda, Us[li], O2, (void*)PQ, O2, C, nullptr, nullptr);
    int nblk = BATCH * NPTS / 4;
    if (O == 64)
      gathermax_kernel<1><<<nblk, 256, 0, stream>>>(PQ, idxb, hmax, O, pbuf);
    else if (O == 128)
      gathermax_kernel<2><<<nblk, 256, 0, stream>>>(PQ, idxb, hmax, O, pbuf);
    else
      gathermax_kernel<4><<<nblk, 256, 0, stream>>>(PQ, idxb, hmax, O, pbuf);
    bn_reduce_finalize<<<O, 256, 0, stream>>>(pbuf, nblk, O, gv[li], bvv[li],
                                              1.0 / ((double)BATCH * NPTS * KNN), sv[li], tv[li]);
    int logO = (O == 64) ? 6 : (O == 128) ? 7 : 8;
    int total = BATCH * NPTS * O;
    apply_kernel<<<(total + 255) / 256, 256, 0, stream>>>(hmax, sv[li], tv[li], feat, featbf,
                                                          colOff, logO, total);
  };

  edge(0, xb, 3, 3, 64, 0);
  edge(1, feat, 512, 64, 64, 64);
  edge(2, feat + 64, 512, 64, 128, 128);
  edge(3, feat + 128, 512, 128, 256, 256);

  fc_mfma_kernel<<<dim3(1024 / 128, BATCH * NPTS / 128), 256, 0, stream>>>(featbf, w5bf, h5, pbuf);
  bn_reduce_finalize<<<1024, 256, 0, stream>>>(pbuf, 64, 1024, gv[4], bvv[4],
                                               1.0 / ((double)BATCH * NPTS), sv[4], tv[4]);
  out_kernel<<<dim3(NPTS / 32, 1024 / 32, BATCH), 256, 0, stream>>>(h5, sv[4], tv[4], out);
}

// Round 5
// 566.481 us; speedup vs baseline: 1.0589x; 1.0149x over previous
//
#include <hip/hip_runtime.h>
#include <cmath>

#define KNN 20
#define NPTS 4096
#define BATCH 2
#define SLOPE 0.2f
#define BNEPS 1e-5
#define GTK 16
#define MAXCAND 256

typedef unsigned short u16;
typedef __attribute__((ext_vector_type(8))) short bf16x8;
typedef __attribute__((ext_vector_type(4))) float f32x4;
typedef _Float16 h8 __attribute__((ext_vector_type(8)));
typedef _Float16 h4 __attribute__((ext_vector_type(4)));

static __device__ __host__ inline int imin(int a, int b) { return a < b ? a : b; }

__device__ inline u16 f2bf(float v) {
  unsigned x = __float_as_uint(v);
  unsigned rr = x + 0x7fff + ((x >> 16) & 1);
  return (u16)(rr >> 16);
}

// ---------------- utility kernels ----------------
// x (B,3,N) -> xb (B,N,3)
__global__ void xtrans_kernel(const float* __restrict__ x, float* __restrict__ xb) {
  int i = blockIdx.x * 256 + threadIdx.x;
  if (i < BATCH * 3 * NPTS) {
    int b = i / (3 * NPTS);
    int r = i - b * 3 * NPTS;
    int c = r / NPTS;
    int n = r - c * NPTS;
    xb[((size_t)b * NPTS + n) * 3 + c] = x[i];
  }
}

// W (O, 2C) -> U (C, 2O): U[j][o]=W[o][j]; U[j][O+o]=W[o][C+j]-W[o][j]
__global__ void uprep_kernel(const float* __restrict__ W, float* __restrict__ U, int O, int C) {
  int i = blockIdx.x * 256 + threadIdx.x;
  if (i < C * O) {
    int j = i / O, o = i - j * O;
    float w1 = W[(size_t)o * 2 * C + j];
    float w2 = W[(size_t)o * 2 * C + C + j];
    U[(size_t)j * 2 * O + o] = w1;
    U[(size_t)j * 2 * O + O + o] = w2 - w1;
  }
}

// squared norms per point (fp64 accumulate, fp32 store — candidate pass only)
__global__ void xx_kernel(const float* __restrict__ X, int stride, int C, float* __restrict__ xx) {
  int i = blockIdx.x * 256 + threadIdx.x;
  if (i < BATCH * NPTS) {
    const float* r = X + (size_t)i * stride;
    double s = 0.0;
    for (int c = 0; c < C; ++c) s += (double)r[c] * (double)r[c];
    xx[i] = (float)s;
  }
}

// fp32 -> bf16 (RNE), 4 elements/thread
__global__ void tobf16_kernel(const float* __restrict__ src, u16* __restrict__ dst, int n4) {
  int i = blockIdx.x * 256 + threadIdx.x;
  if (i < n4) {
    float4 v = *(const float4*)&src[(size_t)i * 4];
    unsigned o[4];
#pragma unroll
    for (int j = 0; j < 4; ++j) o[j] = f2bf(((const float*)&v)[j]);
    uint2 pk;
    pk.x = o[0] | (o[1] << 16);
    pk.y = o[2] | (o[3] << 16);
    *(uint2*)&dst[(size_t)i * 4] = pk;
  }
}

// fp32 X (row-major, lda) -> split hi/lo bf16 (row-major, C), 4 cols/thread
__global__ void tosplit_kernel(const float* __restrict__ X, int lda, int C,
                               u16* __restrict__ hi, u16* __restrict__ lo, int ngroups) {
  int g = blockIdx.x * 256 + threadIdx.x;
  if (g >= ngroups) return;
  int perRow = C >> 2;
  int r = g / perRow;
  int cq = (g - r * perRow) * 4;
  float4 v = *(const float4*)&X[(size_t)r * lda + cq];
  unsigned ho[4], lo_[4];
#pragma unroll
  for (int j = 0; j < 4; ++j) {
    float f = ((const float*)&v)[j];
    u16 h = f2bf(f);
    float hv = __uint_as_float(((unsigned)h) << 16);
    ho[j] = h;
    lo_[j] = f2bf(f - hv);
  }
  uint2 ph, pl;
  ph.x = ho[0] | (ho[1] << 16);
  ph.y = ho[2] | (ho[3] << 16);
  pl.x = lo_[0] | (lo_[1] << 16);
  pl.y = lo_[2] | (lo_[3] << 16);
  size_t di = (size_t)r * C + cq;
  *(uint2*)&hi[di] = ph;
  *(uint2*)&lo[di] = pl;
}

// ---------------- generic 128x128 fp32 GEMM, 8x8 micro (single-buffered) ----------------
// C[M x N] = A[M x K] * (BT ? B[N x K]^T : B[K x N]); DIST epilogue writes fp16.
template <bool BT, bool DIST>
__global__ __launch_bounds__(256) void gemm128(const float* __restrict__ A, int lda,
                                               const float* __restrict__ B, int ldb,
                                               void* __restrict__ Cout, int ldc, int K,
                                               const float* __restrict__ xxA,
                                               const float* __restrict__ xxB) {
  __shared__ __align__(16) float sA[GTK][144];
  __shared__ __align__(16) float sB[GTK][144];
  int t = threadIdx.x;
  int tx = t & 15, ty = t >> 4;
  int row0 = blockIdx.y * 128, col0 = blockIdx.x * 128;
  float acc[8][8] = {};

  for (int k0 = 0; k0 < K; k0 += GTK) {
    bool fast = (k0 + GTK <= K);
    if (fast) {
#pragma unroll
      for (int it = 0; it < 2; ++it) {
        int i = t + it * 256;
        int r = i >> 2, q = i & 3;
        const float4 av = *(const float4*)&A[(size_t)(row0 + r) * lda + k0 + q * 4];
        int pr = r + ((r >> 5) << 2);
        sA[q * 4 + 0][pr] = av.x;
        sA[q * 4 + 1][pr] = av.y;
        sA[q * 4 + 2][pr] = av.z;
        sA[q * 4 + 3][pr] = av.w;
      }
    } else {
#pragma unroll
      for (int it = 0; it < 2; ++it) {
        int i = t + it * 256;
        int r = i >> 2, q = i & 3;
        int pr = r + ((r >> 5) << 2);
#pragma unroll
        for (int j = 0; j < 4; ++j) {
          int k = q * 4 + j;
          sA[k][pr] = (k0 + k < K) ? A[(size_t)(row0 + r) * lda + k0 + k] : 0.f;
        }
      }
    }
    if (BT) {
      if (fast) {
#pragma unroll
        for (int it = 0; it < 2; ++it) {
          int i = t + it * 256;
          int r = i >> 2, q = i & 3;
          const float4 bv = *(const float4*)&B[(size_t)(col0 + r) * ldb + k0 + q * 4];
          int pr = r + ((r >> 5) << 2);
          sB[q * 4 + 0][pr] = bv.x;
          sB[q * 4 + 1][pr] = bv.y;
          sB[q * 4 + 2][pr] = bv.z;
          sB[q * 4 + 3][pr] = bv.w;
        }
      } else {
#pragma unroll
        for (int it = 0; it < 2; ++it) {
          int i = t + it * 256;
          int r = i >> 2, q = i & 3;
          int pr = r + ((r >> 5) << 2);
#pragma unroll
          for (int j = 0; j < 4; ++j) {
            int k = q * 4 + j;
            sB[k][pr] = (k0 + k < K) ? B[(size_t)(col0 + r) * ldb + k0 + k] : 0.f;
          }
        }
      }
    } else {
#pragma unroll
      for (int it = 0; it < 2; ++it) {
        int i = t + it * 256;
        int k = i >> 5, nq = (i & 31) * 4;
        int pc = nq + ((nq >> 5) << 2);
        float4 bv = make_float4(0.f, 0.f, 0.f, 0.f);
        if (k0 + k < K) bv = *(const float4*)&B[(size_t)(k0 + k) * ldb + col0 + nq];
        *(float4*)&sB[k][pc] = bv;
      }
    }
    __syncthreads();
    int prA = ty * 8 + ((ty >> 2) << 2);
    int prB = tx * 8 + ((tx >> 2) << 2);
#pragma unroll
    for (int kk = 0; kk < GTK; ++kk) {
      float a[8], b[8];
      *(float4*)&a[0] = *(const float4*)&sA[kk][prA];
      *(float4*)&a[4] = *(const float4*)&sA[kk][prA + 4];
      *(float4*)&b[0] = *(const float4*)&sB[kk][prB];
      *(float4*)&b[4] = *(const float4*)&sB[kk][prB + 4];
#pragma unroll
      for (int i = 0; i < 8; ++i)
#pragma unroll
        for (int j = 0; j < 8; ++j) acc[i][j] += a[i] * b[j];
    }
    __syncthreads();
  }

  if (DIST) {
    _Float16* Ch = (_Float16*)Cout;
#pragma unroll
    for (int i = 0; i < 8; ++i) {
      int gr = row0 + ty * 8 + i;
      float xa = xxA[gr];
      h8 o;
#pragma unroll
      for (int j = 0; j < 8; ++j) {
        int gc = col0 + tx * 8 + j;
        o[j] = (_Float16)(2.f * acc[i][j] - xa - xxB[gc]);
      }
      *(h8*)&Ch[(size_t)gr * ldc + col0 + tx * 8] = o;
    }
  } else {
    float* Cf = (float*)Cout;
#pragma unroll
    for (int i = 0; i < 8; ++i) {
      int gr = row0 + ty * 8 + i;
#pragma unroll
      for (int jq = 0; jq < 2; ++jq) {
        float4 o;
#pragma unroll
        for (int j = 0; j < 4; ++j) ((float*)&o)[j] = acc[i][jq * 4 + j];
        *(float4*)&Cf[(size_t)gr * ldc + col0 + tx * 8 + jq * 4] = o;
      }
    }
  }
}

// ---------------- split-bf16 MFMA symmetric dist: lower-triangle tiles, mirrored write ----
// <x,y> = hi.hi + hi.lo + lo.hi (3 chained bf16 MFMAs, fp32 acc; lo.lo term ~2^-16 dropped).
// Epilogue: fp16 tile in LDS (rows padded to 136 u16), coalesced h8 writes both orientations.
// grid (ntile, nbatch). Fragment maps identical to fc_mfma (m89-verified).
// LDS layout: 4 slabs of 5120 u16 at offsets a*5120 (Ahi, Alo, Bhi, Blo), rows of 40 u16.
__global__ __launch_bounds__(256) void dist_sym_mfma_kernel(const u16* __restrict__ Xhi,
                                                            const u16* __restrict__ Xlo, int K,
                                                            const float* __restrict__ xx,
                                                            _Float16* __restrict__ dist,
                                                            size_t dstride) {
  __shared__ __align__(16) u16 smem[20544];  // staging 4x128x40 (40960 B) / tile 128x136 (34816 B)
  int t = threadIdx.x;
  int lane = t & 63, wave = t >> 6;
  const u16* xh = Xhi + (size_t)blockIdx.y * NPTS * K;
  const u16* xl = Xlo + (size_t)blockIdx.y * NPTS * K;
  const float* xxv = xx + (size_t)blockIdx.y * NPTS;
  _Float16* db = dist + (size_t)blockIdx.y * dstride;
  int l = blockIdx.x;
  int bi = (int)((sqrtf(8.f * (float)l + 1.f) - 1.f) * 0.5f);
  while ((bi + 1) * (bi + 2) / 2 <= l) ++bi;
  while (bi * (bi + 1) / 2 > l) --bi;
  int bj = l - bi * (bi + 1) / 2;
  int row0 = bi * 128, col0 = bj * 128;
  int wr = (wave >> 1) * 64, wc = (wave & 1) * 64;
  int m = lane & 15, q = lane >> 4;
  f32x4 acc[4][4];
#pragma unroll
  for (int i = 0; i < 4; ++i)
#pragma unroll
    for (int j = 0; j < 4; ++j) acc[i][j] = (f32x4){0.f, 0.f, 0.f, 0.f};

  for (int k0 = 0; k0 < K; k0 += 32) {
#pragma unroll
    for (int it = 0; it < 8; ++it) {
      int e = t + it * 256;
      int a = e >> 9, idx = e & 511;
      int r = idx >> 2, qq = idx & 3;
      const u16* src = (a == 0 || a == 2) ? xh : xl;
      int base = (a < 2) ? row0 : col0;
      *(uint4*)&smem[a * 5120 + r * 40 + qq * 8] =
          *(const uint4*)&src[(size_t)(base + r) * K + k0 + qq * 8];
    }
    __syncthreads();
    bf16x8 ah[4], al[4], bh[4], bl[4];
#pragma unroll
    for (int i = 0; i < 4; ++i) {
      ah[i] = *(const bf16x8*)&smem[0 * 5120 + (wr + i * 16 + m) * 40 + q * 8];
      al[i] = *(const bf16x8*)&smem[1 * 5120 + (wr + i * 16 + m) * 40 + q * 8];
    }
#pragma unroll
    for (int j = 0; j < 4; ++j) {
      bh[j] = *(const bf16x8*)&smem[2 * 5120 + (wc + j * 16 + m) * 40 + q * 8];
      bl[j] = *(const bf16x8*)&smem[3 * 5120 + (wc + j * 16 + m) * 40 + q * 8];
    }
#pragma unroll
    for (int i = 0; i < 4; ++i)
#pragma unroll
      for (int j = 0; j < 4; ++j) {
        acc[i][j] = __builtin_amdgcn_mfma_f32_16x16x32_bf16(ah[i], bh[j], acc[i][j], 0, 0, 0);
        acc[i][j] = __builtin_amdgcn_mfma_f32_16x16x32_bf16(ah[i], bl[j], acc[i][j], 0, 0, 0);
        acc[i][j] = __builtin_amdgcn_mfma_f32_16x16x32_bf16(al[i], bh[j], acc[i][j], 0, 0, 0);
      }
    __syncthreads();
  }

  // DIST transform -> fp16 LDS tile (reuses staging smem; all reads drained by loop-end sync)
  _Float16* tile = (_Float16*)smem;
  {
    float xbv[4];
#pragma unroll
    for (int j = 0; j < 4; ++j) xbv[j] = xxv[col0 + wc + j * 16 + m];
#pragma unroll
    for (int i = 0; i < 4; ++i)
#pragma unroll
      for (int reg = 0; reg < 4; ++reg) {
        int r = wr + i * 16 + q * 4 + reg;
        float xa = xxv[row0 + r];
#pragma unroll
        for (int j = 0; j < 4; ++j)
          tile[r * 136 + wc + j * 16 + m] = (_Float16)(2.f * acc[i][j][reg] - xa - xbv[j]);
      }
  }
  __syncthreads();
  // direct tile (row0, col0): coalesced h8 per 8-col segment
  for (int e = t; e < 2048; e += 256) {
    int r = e >> 4, seg = e & 15;
    *(h8*)&db[(size_t)(row0 + r) * NPTS + col0 + seg * 8] = *(const h8*)&tile[r * 136 + seg * 8];
  }
  // mirrored tile (col0, row0): transposed LDS reads, coalesced global h8 writes
  if (bi != bj) {
    for (int e = t; e < 2048; e += 256) {
      int c = e >> 4, seg = e & 15;
      h8 o;
#pragma unroll
      for (int i = 0; i < 8; ++i) o[i] = tile[(seg * 8 + i) * 136 + c];
      *(h8*)&db[(size_t)(col0 + c) * NPTS + row0 + seg * 8] = o;
    }
  }
}

// ---------------- bf16 MFMA FC: C[8192x1024] = A[8192x512] * B[1024x512]^T ----------------
// Epilogue additionally emits per-block fp64 column sum/sumsq partials (replaces colstats):
// block (cx,ry) owns rows [ry*128,+128) x cols [cx*128,+128); writes pbuf[ry*2048 + col] (sum)
// and pbuf[ry*2048 + 1024 + col] (sumsq) — same layout bn_reduce_finalize(nblk=64) consumes.
__global__ __launch_bounds__(256) void fc_mfma_kernel(const u16* __restrict__ A,
                                                      const u16* __restrict__ B,
                                                      float* __restrict__ C,
                                                      double* __restrict__ pbuf) {
  __shared__ u16 sA[128][56];
  __shared__ u16 sB[128][56];
  __shared__ double sred1[4][64];
  __shared__ double sred2[4][64];
  int t = threadIdx.x;
  int lane = t & 63, wave = t >> 6;
  int row0 = blockIdx.y * 128, col0 = blockIdx.x * 128;
  int wr = (wave >> 1) * 64, wc = (wave & 1) * 64;
  int m = lane & 15, q = lane >> 4;
  f32x4 acc[4][4];
#pragma unroll
  for (int i = 0; i < 4; ++i)
#pragma unroll
    for (int j = 0; j < 4; ++j) acc[i][j] = (f32x4){0.f, 0.f, 0.f, 0.f};
  for (int k0 = 0; k0 < 512; k0 += 32) {
#pragma unroll
    for (int it = 0; it < 2; ++it) {
      int i = t + it * 256;
      int r = i >> 2, ch = (i & 3) * 8;
      *(uint4*)&sA[r][ch] = *(const uint4*)&A[(size_t)(row0 + r) * 512 + k0 + ch];
      *(uint4*)&sB[r][ch] = *(const uint4*)&B[(size_t)(col0 + r) * 512 + k0 + ch];
    }
    __syncthreads();
    bf16x8 af[4], bf[4];
#pragma unroll
    for (int i = 0; i < 4; ++i) af[i] = *(const bf16x8*)&sA[wr + i * 16 + m][q * 8];
#pragma unroll
    for (int j = 0; j < 4; ++j) bf[j] = *(const bf16x8*)&sB[wc + j * 16 + m][q * 8];
#pragma unroll
    for (int i = 0; i < 4; ++i)
#pragma unroll
      for (int j = 0; j < 4; ++j)
        acc[i][j] = __builtin_amdgcn_mfma_f32_16x16x32_bf16(af[i], bf[j], acc[i][j], 0, 0, 0);
    __syncthreads();
  }
#pragma unroll
  for (int i = 0; i < 4; ++i)
#pragma unroll
    for (int j = 0; j < 4; ++j)
#pragma unroll
      for (int reg = 0; reg < 4; ++reg)
        C[(size_t)(row0 + wr + i * 16 + q * 4 + reg) * 1024 + col0 + wc + j * 16 + m] =
            acc[i][j][reg];

  // ---- fused column stats (fp64): per-thread 16 rows, q-group shuffle, wave-pair combine ----
#pragma unroll
  for (int j = 0; j < 4; ++j) {
    double s1 = 0.0, s2 = 0.0;
#pragma unroll
    for (int i = 0; i < 4; ++i)
#pragma unroll
      for (int reg = 0; reg < 4; ++reg) {
        double v = (double)acc[i][j][reg];
        s1 += v;
        s2 += v * v;
      }
    // reduce across q (lanes q*16+m, q=0..3): xor 16 then 32 keeps m fixed
    s1 += __shfl_xor(s1, 16);
    s2 += __shfl_xor(s2, 16);
    s1 += __shfl_xor(s1, 32);
    s2 += __shfl_xor(s2, 32);
    if (q == 0) {
      sred1[wave][j * 16 + m] = s1;
      sred2[wave][j * 16 + m] = s2;
    }
  }
  __syncthreads();
  if (t < 128) {
    int p = t >> 6, u = t & 63;  // p: wc half (waves p and p+2), u = j*16+m
    double a = sred1[p][u] + sred1[p + 2][u];
    double b = sred2[p][u] + sred2[p + 2][u];
    int gcol = col0 + p * 64 + u;
    pbuf[(size_t)blockIdx.y * 2048 + gcol] = a;
    pbuf[(size_t)blockIdx.y * 2048 + 1024 + gcol] = b;
  }
}

// ---------------- shared top-k selection helpers ----------------
__device__ inline bool comp_less(double v, int i, double ov, int oi) {
  return (v < ov) || (v == ov && i > oi);
}

// ---------------- fast top-k: threshold filter (fp16 dist) + fp64 rescore + bitonic sort ---
// Templated on C (64 or 128): full unroll of the rescore distance loop + 4-way fp64
// accumulator ILP. The previous runtime-C loop serialized {load, 8 chained v_fma_f64} per
// iteration (latency-bound: 33% VALUBusy, 13% HBM). Fixed (d0+d1)+(d2+d3) combine order is
// deterministic across candidates; vs old serial order differs by <=1 ulp (tie flips need
// exact fp64 distance ties between distinct points - measure-zero).
template <int C>
__global__ __launch_bounds__(256) void topk_fast_kernel(const _Float16* __restrict__ dist,
                                                        size_t dstride,
                                                        const float* __restrict__ Xb,
                                                        size_t xstride, int lda,
                                                        int* __restrict__ idxout, size_t istride,
                                                        int n0, int rows) {
  __shared__ int scand[4][MAXCAND];
  int wave = threadIdx.x >> 6, lane = threadIdx.x & 63;
  int row = blockIdx.x * 4 + wave;
  if (row >= rows) return;
  const _Float16* distb = dist + (size_t)blockIdx.y * dstride;
  const float* Xbb = Xb + (size_t)blockIdx.y * xstride;
  int* idxb = idxout + (size_t)blockIdx.y * istride;
  const _Float16* d = distb + (size_t)row * NPTS;
  float v[16][4];
  float lmax = -__builtin_inff();
#pragma unroll
  for (int s = 0; s < 16; ++s) {
    h4 hv = *(const h4*)&d[s * 256 + lane * 4];
#pragma unroll
    for (int c = 0; c < 4; ++c) {
      v[s][c] = (float)hv[c];
      lmax = fmaxf(lmax, v[s][c]);
    }
  }

  float sv = lmax;
  for (int k = 2; k <= 64; k <<= 1) {
    for (int j = k >> 1; j > 0; j >>= 1) {
      float ov = __shfl_xor(sv, j);
      bool up = ((lane & k) == 0);
      bool lower = ((lane & j) == 0);
      bool mineLess = sv < ov;
      bool keepMine = (up == lower) ? mineLess : !mineLess;
      sv = keepMine ? sv : ov;
    }
  }
  float T = __shfl(sv, 44);

  int myCnt = 0;
#pragma unroll
  for (int s = 0; s < 16; ++s)
#pragma unroll
    for (int c = 0; c < 4; ++c) myCnt += (v[s][c] >= T) ? 1 : 0;
  int ofs = myCnt;
  for (int dlt = 1; dlt < 64; dlt <<= 1) {
    int o = __shfl_up(ofs, dlt);
    if (lane >= dlt) ofs += o;
  }
  int total = __shfl(ofs, 63);
  ofs -= myCnt;
  int w = ofs;
#pragma unroll
  for (int s = 0; s < 16; ++s)
#pragma unroll
    for (int c = 0; c < 4; ++c) {
      if (v[s][c] >= T) {
        if (w < MAXCAND) scand[wave][w] = s * 256 + lane * 4 + c;
        ++w;
      }
    }
  int cnt = imin(total, MAXCAND);
  int gn = n0 + row;
  const float* crow = Xbb + (size_t)gn * lda;
  int nch = (cnt + 63) >> 6;

  double runV = -__builtin_inf();
  int runI = 0x7fffffff;
  for (int ch = 0; ch < nch; ++ch) {
    int slot = ch * 64 + lane;
    int m = (slot < cnt) ? scand[wave][slot] : -1;
    double val = -__builtin_inf();
    int vi = 0x7fffffff;
    if (m >= 0) {
      const float* mrow = Xbb + (size_t)m * lda;
      double d0 = 0.0, d1 = 0.0, d2 = 0.0, d3 = 0.0;
#pragma unroll
      for (int c = 0; c < C; c += 4) {
        float4 a = *(const float4*)&crow[c];
        float4 b = *(const float4*)&mrow[c];
        double f0 = (double)a.x - (double)b.x;
        double f1 = (double)a.y - (double)b.y;
        double f2 = (double)a.z - (double)b.z;
        double f3 = (double)a.w - (double)b.w;
        d0 = fma(f0, f0, d0);
        d1 = fma(f1, f1, d1);
        d2 = fma(f2, f2, d2);
        d3 = fma(f3, f3, d3);
      }
      val = -((d0 + d1) + (d2 + d3));
      vi = m;
    }
    for (int k = 2; k <= 64; k <<= 1) {
      for (int j = k >> 1; j > 0; j >>= 1) {
        double ov = __shfl_xor(val, j);
        int oi = __shfl_xor(vi, j);
        bool up = ((lane & k) == 0);
        bool lower = ((lane & j) == 0);
        bool mineLess = comp_less(val, vi, ov, oi);
        bool keepMine = (up == lower) ? mineLess : !mineLess;
        if (!keepMine) { val = ov; vi = oi; }
      }
    }
    if (ch == 0) {
      runV = val;
      runI = vi;
    } else {
      double rv = __shfl(val, 63 - lane);
      int ri = __shfl(vi, 63 - lane);
      if (comp_less(runV, runI, rv, ri)) { runV = rv; runI = ri; }
      for (int j = 32; j > 0; j >>= 1) {
        double ov = __shfl_xor(runV, j);
        int oi = __shfl_xor(runI, j);
        bool lower = ((lane & j) == 0);
        bool mineLess = comp_less(runV, runI, ov, oi);
        bool keepMine = lower ? mineLess : !mineLess;
        if (!keepMine) { runV = ov; runI = oi; }
      }
    }
  }
  if (lane >= 44) idxb[(size_t)gn * KNN + (63 - lane)] = runI;
}

// ---------------- fused layer-1 kNN (C=3): whole point set in LDS ----------------
// 512 threads = 8 waves/block, 8 rows/block, register-cached v[16][4] per wave
// (~88 VGPR -> 4 waves/SIMD band). LDS = 48K xyz + 4K u16 scand = 52K -> 2-3 blocks/CU,
// 16 waves/CU (VGPR-capped). This is the round-2 body (best measured: ~43 µs);
// round-3's recompute variant regressed (VGPR 108, +2x VALU). NO min-waves bound
// (forcing 8/EU clamps VGPR to 32 -> 600 MB/dispatch scratch spill).
__global__ __launch_bounds__(512) void dist3_topk_kernel(const float* __restrict__ Xb,
                                                         int* __restrict__ idxout) {
  __shared__ float xs[NPTS], ys[NPTS], zs[NPTS];
  __shared__ u16 scand[8][MAXCAND];
  int t = threadIdx.x;
  const float* Xbb = Xb + (size_t)blockIdx.y * NPTS * 3;
  for (int i = t; i < NPTS * 3; i += 512) {
    int n = i / 3, c = i - n * 3;
    float v = Xbb[i];
    if (c == 0) xs[n] = v;
    else if (c == 1) ys[n] = v;
    else zs[n] = v;
  }
  __syncthreads();
  int wave = t >> 6, lane = t & 63;
  int row = blockIdx.x * 8 + wave;
  float cx = xs[row], cy = ys[row], cz = zs[row];
  float v[16][4];
  float lmax = -__builtin_inff();
#pragma unroll
  for (int s = 0; s < 16; ++s)
#pragma unroll
    for (int c = 0; c < 4; ++c) {
      int m = s * 256 + c * 64 + lane;
      float dx = cx - xs[m], dy = cy - ys[m], dz = cz - zs[m];
      float dv = -(dx * dx + dy * dy + dz * dz);
      v[s][c] = dv;
      lmax = fmaxf(lmax, dv);
    }

  float sv = lmax;
  for (int k = 2; k <= 64; k <<= 1) {
    for (int j = k >> 1; j > 0; j >>= 1) {
      float ov = __shfl_xor(sv, j);
      bool up = ((lane & k) == 0);
      bool lower = ((lane & j) == 0);
      bool mineLess = sv < ov;
      bool keepMine = (up == lower) ? mineLess : !mineLess;
      sv = keepMine ? sv : ov;
    }
  }
  float T = __shfl(sv, 44);

  int myCnt = 0;
#pragma unroll
  for (int s = 0; s < 16; ++s)
#pragma unroll
    for (int c = 0; c < 4; ++c) myCnt += (v[s][c] >= T) ? 1 : 0;
  int ofs = myCnt;
  for (int dlt = 1; dlt < 64; dlt <<= 1) {
    int o = __shfl_up(ofs, dlt);
    if (lane >= dlt) ofs += o;
  }
  int total = __shfl(ofs, 63);
  ofs -= myCnt;
  int w = ofs;
#pragma unroll
  for (int s = 0; s < 16; ++s)
#pragma unroll
    for (int c = 0; c < 4; ++c) {
      if (v[s][c] >= T) {
        if (w < MAXCAND) scand[wave][w] = (u16)(s * 256 + c * 64 + lane);
        ++w;
      }
    }
  int cnt = imin(total, MAXCAND);
  int nch = (cnt + 63) >> 6;

  double runV = -__builtin_inf();
  int runI = 0x7fffffff;
  for (int ch = 0; ch < nch; ++ch) {
    int slot = ch * 64 + lane;
    int m = (slot < cnt) ? (int)scand[wave][slot] : -1;
    double val = -__builtin_inf();
    int vi = 0x7fffffff;
    if (m >= 0) {
      double dx = (double)cx - (double)xs[m];
      double dy = (double)cy - (double)ys[m];
      double dz = (double)cz - (double)zs[m];
      val = -(dx * dx + dy * dy + dz * dz);
      vi = m;
    }
    for (int k = 2; k <= 64; k <<= 1) {
      for (int j = k >> 1; j > 0; j >>= 1) {
        double ov = __shfl_xor(val, j);
        int oi = __shfl_xor(vi, j);
        bool up = ((lane & k) == 0);
        bool lower = ((lane & j) == 0);
        bool mineLess = comp_less(val, vi, ov, oi);
        bool keepMine = (up == lower) ? mineLess : !mineLess;
        if (!keepMine) { val = ov; vi = oi; }
      }
    }
    if (ch == 0) {
      runV = val;
      runI = vi;
    } else {
      double rv = __shfl(val, 63 - lane);
      int ri = __shfl(vi, 63 - lane);
      if (comp_less(runV, runI, rv, ri)) { runV = rv; runI = ri; }
      for (int j = 32; j > 0; j >>= 1) {
        double ov = __shfl_xor(runV, j);
        int oi = __shfl_xor(runI, j);
        bool lower = ((lane & j) == 0);
        bool mineLess = comp_less(runV, runI, ov, oi);
        bool keepMine = lower ? mineLess : !mineLess;
        if (!keepMine) { runV = ov; runI = oi; }
      }
    }
  }
  if (lane >= 44)
    idxout[((size_t)blockIdx.y * NPTS + row) * KNN + (63 - lane)] = runI;
}

// ---------------- gather-max + per-block fp64 BN partial stats ----------------
template <int NO>
__global__ __launch_bounds__(256) void gathermax_kernel(const float* __restrict__ PQ,
                                                        const int* __restrict__ idx,
                                                        float* __restrict__ hmax, int O,
                                                        double* __restrict__ pbuf) {
  __shared__ double sh1[4][256];
  __shared__ double sh2[4][256];
  int t = threadIdx.x;
  int wave = t >> 6, lane = t & 63;
  int pt = blockIdx.x * 4 + wave;
  int b = pt >> 12;
  int O2 = 2 * O;
  int iv = idx[(size_t)pt * KNN + (lane % KNN)];
  const float* Qp = PQ + (size_t)pt * O2 + O + lane * NO;
  float q[NO], mx[NO];
  double s1[NO], s2[NO];
#pragma unroll
  for (int c = 0; c < NO; ++c) {
    q[c] = Qp[c];
    mx[c] = -__builtin_inff();
    s1[c] = 0.0;
    s2[c] = 0.0;
  }
#pragma unroll
  for (int k = 0; k < KNN; ++k) {
    int m = __shfl(iv, k);
    const float* Pp = PQ + ((size_t)(b << 12) + m) * O2 + lane * NO;
    float p[NO];
#pragma unroll
    for (int c = 0; c < NO; ++c) p[c] = Pp[c];
#pragma unroll
    for (int c = 0; c < NO; ++c) {
      float h = p[c] + q[c];
      mx[c] = fmaxf(mx[c], h);
      double hd = (double)h;
      s1[c] += hd;
      s2[c] += hd * hd;
    }
  }
  float* Hp = hmax + (size_t)pt * O + lane * NO;
#pragma unroll
  for (int c = 0; c < NO; ++c) {
    Hp[c] = mx[c];
    sh1[wave][lane * NO + c] = s1[c];
    sh2[wave][lane * NO + c] = s2[c];
  }
  __syncthreads();
  if (t < O) {
    double a = 0.0, bb = 0.0;
#pragma unroll
    for (int w = 0; w < 4; ++w) {
      a += sh1[w][t];
      bb += sh2[w][t];
    }
    pbuf[(size_t)blockIdx.x * O2 + t] = a;
    pbuf[(size_t)blockIdx.x * O2 + O + t] = bb;
  }
}

// ---------------- deterministic parallel fp64 BN reduce + finalize ----------------
__global__ __launch_bounds__(256) void bn_reduce_finalize(const double* __restrict__ pbuf,
                                                          int nblk, int O,
                                                          const float* __restrict__ g,
                                                          const float* __restrict__ bb,
                                                          double invcount,
                                                          float* __restrict__ s_out,
                                                          float* __restrict__ t_out) {
  __shared__ double sh1[256];
  __shared__ double sh2[256];
  int o = blockIdx.x;
  int t = threadIdx.x;
  double s1 = 0.0, s2 = 0.0;
  for (int blk = t; blk < nblk; blk += 256) {
    s1 += pbuf[(size_t)blk * 2 * O + o];
    s2 += pbuf[(size_t)blk * 2 * O + O + o];
  }
  sh1[t] = s1;
  sh2[t] = s2;
  __syncthreads();
  for (int s = 128; s > 0; s >>= 1) {
    if (t < s) {
      sh1[t] += sh1[t + s];
      sh2[t] += sh2[t + s];
    }
    __syncthreads();
  }
  if (t == 0) {
    double mean = sh1[0] * invcount;
    double var = sh2[0] * invcount - mean * mean;
    double s = (double)g[o] / sqrt(var + BNEPS);
    s_out[o] = (float)s;
    t_out[o] = (float)((double)bb[o] - mean * s);
  }
}

// y = leaky(hmax*s+t) into feat column slice (fp32) + featbf (bf16, fused conversion)
__global__ void apply_kernel(const float* __restrict__ hmax, const float* __restrict__ s,
                             const float* __restrict__ tt, float* __restrict__ feat,
                             u16* __restrict__ featbf, int colOff, int logO, int total) {
  int i = blockIdx.x * 256 + threadIdx.x;
  if (i >= total) return;
  int O = 1 << logO;
  int o = i & (O - 1);
  int pp = i >> logO;
  float v = hmax[i] * s[o] + tt[o];
  float r = v > 0.f ? v : SLOPE * v;
  size_t di = (size_t)pp * 512 + colOff + o;
  feat[di] = r;
  featbf[di] = f2bf(r);
}

// out[b][o][n] = leaky(h5[b][n][o]*s+t)
__global__ void out_kernel(const float* __restrict__ h5, const float* __restrict__ s,
                           const float* __restrict__ tt, float* __restrict__ out) {
  __shared__ float tile[32][33];
  int b = blockIdx.z;
  int n0 = blockIdx.x * 32, o0 = blockIdx.y * 32;
  int t = threadIdx.x;
  for (int e = t; e < 1024; e += 256) {
    int rn = e >> 5, co = e & 31;
    int o = o0 + co;
    float v = h5[((size_t)b * NPTS + n0 + rn) * 1024 + o] * s[o] + tt[o];
    tile[rn][co] = v > 0.f ? v : SLOPE * v;
  }
  __syncthreads();
  for (int e = t; e < 1024; e += 256) {
    int ro = e >> 5, cn = e & 31;
    out[((size_t)b * 1024 + o0 + ro) * NPTS + n0 + cn] = tile[cn][ro];
  }
}

// ---------------- host ----------------
extern "C" void kernel_launch(void* const* d_in, const int* in_sizes, int n_in,
                              void* d_out, int out_size, void* d_ws, size_t ws_size,
                              hipStream_t stream) {
  const float* x = (const float*)d_in[0];
  const float* Wm[5] = {(const float*)d_in[1], (const float*)d_in[4], (const float*)d_in[7],
                        (const float*)d_in[10], (const float*)d_in[13]};
  const float* gv[5] = {(const float*)d_in[2], (const float*)d_in[5], (const float*)d_in[8],
                        (const float*)d_in[11], (const float*)d_in[14]};
  const float* bvv[5] = {(const float*)d_in[3], (const float*)d_in[6], (const float*)d_in[9],
                         (const float*)d_in[12], (const float*)d_in[15]};
  float* out = (float*)d_out;

  char* wsb = (char*)d_ws;
  size_t off = 0;
  auto alloc = [&](size_t bytes) -> char* {
    off = (off + 255) & ~(size_t)255;
    char* p = wsb + off;
    off += bytes;
    return p;
  };
  float* xb = (float*)alloc((size_t)BATCH * NPTS * 3 * 4);
  float* xxb = (float*)alloc((size_t)BATCH * NPTS * 4);
  int* idxb = (int*)alloc((size_t)BATCH * NPTS * KNN * 4);
  float* feat = (float*)alloc((size_t)BATCH * NPTS * 512 * 4);
  float* hmax = (float*)alloc((size_t)BATCH * NPTS * 256 * 4);
  float* h5 = (float*)alloc((size_t)BATCH * NPTS * 1024 * 4);
  float* PQ = h5;  // alias: PQ used per-layer, h5 only needed after
  float* U1 = (float*)alloc(3 * 128 * 4);
  float* U2 = (float*)alloc(64 * 128 * 4);
  float* U3 = (float*)alloc(64 * 256 * 4);
  float* U4 = (float*)alloc(128 * 512 * 4);
  u16* featbf = (u16*)alloc((size_t)BATCH * NPTS * 512 * 2);
  u16* w5bf = (u16*)alloc((size_t)1024 * 512 * 2);
  u16* xhi = (u16*)alloc((size_t)BATCH * NPTS * 128 * 2);
  u16* xlo = (u16*)alloc((size_t)BATCH * NPTS * 128 * 2);
  double* pbuf = (double*)alloc((size_t)2048 * 512 * 8);
  float* stv = (float*)alloc(3072 * 4);
  off = (off + 255) & ~(size_t)255;
  size_t avail = (ws_size > off) ? (ws_size - off) : 0;
  size_t slab = (size_t)NPTS * NPTS * 2;              // one batch's fp16 dist matrix
  int nbfit = (int)imin((int)(avail / slab), BATCH);  // 0, 1, or 2 slabs fit
  size_t rmax = avail / ((size_t)NPTS * 2);
  int R;
  if (rmax >= NPTS) R = NPTS;
  else {
    R = (int)(rmax & ~(size_t)127);
    if (R < 128) R = 128;
  }
  _Float16* distbuf = (_Float16*)(wsb + off);

  float* sv[5] = {stv + 0, stv + 128, stv + 256, stv + 512, stv + 1024};
  float* tv[5] = {stv + 64, stv + 192, stv + 384, stv + 768, stv + 2048};
  float* Us[4] = {U1, U2, U3, U4};
  const int Cs[4] = {3, 64, 64, 128};
  const int Osz[4] = {64, 64, 128, 256};
  const int ntile = (NPTS / 128) * (NPTS / 128 + 1) / 2;  // 528

  xtrans_kernel<<<(BATCH * 3 * NPTS + 255) / 256, 256, 0, stream>>>(x, xb);
  for (int l = 0; l < 4; ++l)
    uprep_kernel<<<(Cs[l] * Osz[l] + 255) / 256, 256, 0, stream>>>(Wm[l], Us[l], Osz[l], Cs[l]);
  tobf16_kernel<<<(1024 * 512 / 4 + 255) / 256, 256, 0, stream>>>(Wm[4], w5bf, 1024 * 512 / 4);

  auto launch_topk = [&](int C, dim3 grid, const _Float16* db, size_t dstride, const float* Xb,
                         size_t xstride, int lda, int* idxo, size_t istride, int n0, int rows) {
    if (C == 64)
      topk_fast_kernel<64><<<grid, 256, 0, stream>>>(db, dstride, Xb, xstride, lda, idxo, istride,
                                                     n0, rows);
    else
      topk_fast_kernel<128><<<grid, 256, 0, stream>>>(db, dstride, Xb, xstride, lda, idxo, istride,
                                                      n0, rows);
  };

  auto knn = [&](const float* Xbase, int lda, int C) {
    xx_kernel<<<(BATCH * NPTS + 255) / 256, 256, 0, stream>>>(Xbase, lda, C, xxb);
    size_t selems = (size_t)NPTS * NPTS;
    if (nbfit >= 1) {
      int ngroups = BATCH * NPTS * (C / 4);
      tosplit_kernel<<<(ngroups + 255) / 256, 256, 0, stream>>>(Xbase, lda, C, xhi, xlo, ngroups);
    }
    if (nbfit >= BATCH) {
      dist_sym_mfma_kernel<<<dim3(ntile, BATCH), 256, 0, stream>>>(xhi, xlo, C, xxb, distbuf,
                                                                   selems);
      launch_topk(C, dim3(NPTS / 4, BATCH), distbuf, selems, Xbase, (size_t)NPTS * lda, lda, idxb,
                  (size_t)NPTS * KNN, 0, NPTS);
    } else if (nbfit >= 1) {
      for (int b = 0; b < BATCH; ++b) {
        const float* Xb = Xbase + (size_t)b * NPTS * lda;
        dist_sym_mfma_kernel<<<dim3(ntile, 1), 256, 0, stream>>>(
            xhi + (size_t)b * NPTS * C, xlo + (size_t)b * NPTS * C, C, xxb + (size_t)b * NPTS,
            distbuf, 0);
        launch_topk(C, dim3(NPTS / 4, 1), distbuf, 0, Xb, 0, lda, idxb + (size_t)b * NPTS * KNN, 0,
                    0, NPTS);
      }
    } else {
      for (int b = 0; b < BATCH; ++b) {
        const float* Xb = Xbase + (size_t)b * NPTS * lda;
        for (int n0 = 0; n0 < NPTS; n0 += R) {
          int rows = imin(R, NPTS - n0);
          gemm128<true, true><<<dim3(NPTS / 128, rows / 128), 256, 0, stream>>>(
              Xb + (size_t)n0 * lda, lda, Xb, lda, (void*)distbuf, NPTS, C,
              xxb + (size_t)b * NPTS + n0, xxb + (size_t)b * NPTS);
          launch_topk(C, dim3(rows / 4, 1), distbuf, 0, Xb, 0, lda, idxb + (size_t)b * NPTS * KNN,
                      0, n0, rows);
        }
      }
    }
  };

  auto edge = [&](int li, const float* Xbase, int lda, int C, int O, int colOff) {
    if (li == 0) {
      dist3_topk_kernel<<<dim3(NPTS / 8, BATCH), 512, 0, stream>>>(Xbase, idxb);
    } else {
      knn(Xbase, lda, C);
    }
    int O2 = 2 * O;
    gemm128<false, false><<<dim3(O2 / 128, BATCH * NPTS / 128), 256, 0, stream>>>(
        Xbase, lda, Us[li], O2, (void*)PQ, O2, C, nullptr, nullptr);
    int nblk = BATCH * NPTS / 4;
    if (O == 64)
      gathermax_kernel<1><<<nblk, 256, 0, stream>>>(PQ, idxb, hmax, O, pbuf);
    else if (O == 128)
      gathermax_kernel<2><<<nblk, 256, 0, stream>>>(PQ, idxb, hmax, O, pbuf);
    else
      gathermax_kernel<4><<<nblk, 256, 0, stream>>>(PQ, idxb, hmax, O, pbuf);
    bn_reduce_finalize<<<O, 256, 0, stream>>>(pbuf, nblk, O, gv[li], bvv[li],
                                              1.0 / ((double)BATCH * NPTS * KNN), sv[li], tv[li]);
    int logO = (O == 64) ? 6 : (O == 128) ? 7 : 8;
    int total = BATCH * NPTS * O;
    apply_kernel<<<(total + 255) / 256, 256, 0, stream>>>(hmax, sv[li], tv[li], feat, featbf,
                                                          colOff, logO, total);
  };

  edge(0, xb, 3, 3, 64, 0);
  edge(1, feat, 512, 64, 64, 64);
  edge(2, feat + 64, 512, 64, 128, 128);
  edge(3, feat + 128, 512, 128, 256, 256);

  fc_mfma_kernel<<<dim3(1024 / 128, BATCH * NPTS / 128), 256, 0, stream>>>(featbf, w5bf, h5, pbuf);
  bn_reduce_finalize<<<1024, 256, 0, stream>>>(pbuf, 64, 1024, gv[4], bvv[4],
                                               1.0 / ((double)BATCH * NPTS), sv[4], tv[4]);
  out_kernel<<<dim3(NPTS / 32, 1024 / 32, BATCH), 256, 0, stream>>>(h5, sv[4], tv[4], out);
}

// Round 6
// 565.949 us; speedup vs baseline: 1.0599x; 1.0009x over previous
//
#include <hip/hip_runtime.h>
#include <cmath>

#define KNN 20
#define NPTS 4096
#define BATCH 2
#define SLOPE 0.2f
#define BNEPS 1e-5
#define GTK 16
#define MAXCAND 256

typedef unsigned short u16;
typedef __attribute__((ext_vector_type(8))) short bf16x8;
typedef __attribute__((ext_vector_type(4))) float f32x4;
typedef _Float16 h8 __attribute__((ext_vector_type(8)));
typedef _Float16 h4 __attribute__((ext_vector_type(4)));

static __device__ __host__ inline int imin(int a, int b) { return a < b ? a : b; }

__device__ inline u16 f2bf(float v) {
  unsigned x = __float_as_uint(v);
  unsigned rr = x + 0x7fff + ((x >> 16) & 1);
  return (u16)(rr >> 16);
}

// ---------------- utility kernels ----------------
// x (B,3,N) -> xb (B,N,3)
__global__ void xtrans_kernel(const float* __restrict__ x, float* __restrict__ xb) {
  int i = blockIdx.x * 256 + threadIdx.x;
  if (i < BATCH * 3 * NPTS) {
    int b = i / (3 * NPTS);
    int r = i - b * 3 * NPTS;
    int c = r / NPTS;
    int n = r - c * NPTS;
    xb[((size_t)b * NPTS + n) * 3 + c] = x[i];
  }
}

// W (O, 2C) -> U (C, 2O): U[j][o]=W[o][j]; U[j][O+o]=W[o][C+j]-W[o][j]
__global__ void uprep_kernel(const float* __restrict__ W, float* __restrict__ U, int O, int C) {
  int i = blockIdx.x * 256 + threadIdx.x;
  if (i < C * O) {
    int j = i / O, o = i - j * O;
    float w1 = W[(size_t)o * 2 * C + j];
    float w2 = W[(size_t)o * 2 * C + C + j];
    U[(size_t)j * 2 * O + o] = w1;
    U[(size_t)j * 2 * O + O + o] = w2 - w1;
  }
}

// squared norms per point (fp64 accumulate, fp32 store — candidate pass only)
__global__ void xx_kernel(const float* __restrict__ X, int stride, int C, float* __restrict__ xx) {
  int i = blockIdx.x * 256 + threadIdx.x;
  if (i < BATCH * NPTS) {
    const float* r = X + (size_t)i * stride;
    double s = 0.0;
    for (int c = 0; c < C; ++c) s += (double)r[c] * (double)r[c];
    xx[i] = (float)s;
  }
}

// fp32 -> bf16 (RNE), 4 elements/thread
__global__ void tobf16_kernel(const float* __restrict__ src, u16* __restrict__ dst, int n4) {
  int i = blockIdx.x * 256 + threadIdx.x;
  if (i < n4) {
    float4 v = *(const float4*)&src[(size_t)i * 4];
    unsigned o[4];
#pragma unroll
    for (int j = 0; j < 4; ++j) o[j] = f2bf(((const float*)&v)[j]);
    uint2 pk;
    pk.x = o[0] | (o[1] << 16);
    pk.y = o[2] | (o[3] << 16);
    *(uint2*)&dst[(size_t)i * 4] = pk;
  }
}

// fp32 X (row-major, lda) -> split hi/lo bf16 (row-major, C), 4 cols/thread
__global__ void tosplit_kernel(const float* __restrict__ X, int lda, int C,
                               u16* __restrict__ hi, u16* __restrict__ lo, int ngroups) {
  int g = blockIdx.x * 256 + threadIdx.x;
  if (g >= ngroups) return;
  int perRow = C >> 2;
  int r = g / perRow;
  int cq = (g - r * perRow) * 4;
  float4 v = *(const float4*)&X[(size_t)r * lda + cq];
  unsigned ho[4], lo_[4];
#pragma unroll
  for (int j = 0; j < 4; ++j) {
    float f = ((const float*)&v)[j];
    u16 h = f2bf(f);
    float hv = __uint_as_float(((unsigned)h) << 16);
    ho[j] = h;
    lo_[j] = f2bf(f - hv);
  }
  uint2 ph, pl;
  ph.x = ho[0] | (ho[1] << 16);
  ph.y = ho[2] | (ho[3] << 16);
  pl.x = lo_[0] | (lo_[1] << 16);
  pl.y = lo_[2] | (lo_[3] << 16);
  size_t di = (size_t)r * C + cq;
  *(uint2*)&hi[di] = ph;
  *(uint2*)&lo[di] = pl;
}

// ---------------- generic 128x128 fp32 GEMM, 8x8 micro (single-buffered) ----------------
// C[M x N] = A[M x K] * (BT ? B[N x K]^T : B[K x N]); DIST epilogue writes fp16.
template <bool BT, bool DIST>
__global__ __launch_bounds__(256) void gemm128(const float* __restrict__ A, int lda,
                                               const float* __restrict__ B, int ldb,
                                               void* __restrict__ Cout, int ldc, int K,
                                               const float* __restrict__ xxA,
                                               const float* __restrict__ xxB) {
  __shared__ __align__(16) float sA[GTK][144];
  __shared__ __align__(16) float sB[GTK][144];
  int t = threadIdx.x;
  int tx = t & 15, ty = t >> 4;
  int row0 = blockIdx.y * 128, col0 = blockIdx.x * 128;
  float acc[8][8] = {};

  for (int k0 = 0; k0 < K; k0 += GTK) {
    bool fast = (k0 + GTK <= K);
    if (fast) {
#pragma unroll
      for (int it = 0; it < 2; ++it) {
        int i = t + it * 256;
        int r = i >> 2, q = i & 3;
        const float4 av = *(const float4*)&A[(size_t)(row0 + r) * lda + k0 + q * 4];
        int pr = r + ((r >> 5) << 2);
        sA[q * 4 + 0][pr] = av.x;
        sA[q * 4 + 1][pr] = av.y;
        sA[q * 4 + 2][pr] = av.z;
        sA[q * 4 + 3][pr] = av.w;
      }
    } else {
#pragma unroll
      for (int it = 0; it < 2; ++it) {
        int i = t + it * 256;
        int r = i >> 2, q = i & 3;
        int pr = r + ((r >> 5) << 2);
#pragma unroll
        for (int j = 0; j < 4; ++j) {
          int k = q * 4 + j;
          sA[k][pr] = (k0 + k < K) ? A[(size_t)(row0 + r) * lda + k0 + k] : 0.f;
        }
      }
    }
    if (BT) {
      if (fast) {
#pragma unroll
        for (int it = 0; it < 2; ++it) {
          int i = t + it * 256;
          int r = i >> 2, q = i & 3;
          const float4 bv = *(const float4*)&B[(size_t)(col0 + r) * ldb + k0 + q * 4];
          int pr = r + ((r >> 5) << 2);
          sB[q * 4 + 0][pr] = bv.x;
          sB[q * 4 + 1][pr] = bv.y;
          sB[q * 4 + 2][pr] = bv.z;
          sB[q * 4 + 3][pr] = bv.w;
        }
      } else {
#pragma unroll
        for (int it = 0; it < 2; ++it) {
          int i = t + it * 256;
          int r = i >> 2, q = i & 3;
          int pr = r + ((r >> 5) << 2);
#pragma unroll
          for (int j = 0; j < 4; ++j) {
            int k = q * 4 + j;
            sB[k][pr] = (k0 + k < K) ? B[(size_t)(col0 + r) * ldb + k0 + k] : 0.f;
          }
        }
      }
    } else {
#pragma unroll
      for (int it = 0; it < 2; ++it) {
        int i = t + it * 256;
        int k = i >> 5, nq = (i & 31) * 4;
        int pc = nq + ((nq >> 5) << 2);
        float4 bv = make_float4(0.f, 0.f, 0.f, 0.f);
        if (k0 + k < K) bv = *(const float4*)&B[(size_t)(k0 + k) * ldb + col0 + nq];
        *(float4*)&sB[k][pc] = bv;
      }
    }
    __syncthreads();
    int prA = ty * 8 + ((ty >> 2) << 2);
    int prB = tx * 8 + ((tx >> 2) << 2);
#pragma unroll
    for (int kk = 0; kk < GTK; ++kk) {
      float a[8], b[8];
      *(float4*)&a[0] = *(const float4*)&sA[kk][prA];
      *(float4*)&a[4] = *(const float4*)&sA[kk][prA + 4];
      *(float4*)&b[0] = *(const float4*)&sB[kk][prB];
      *(float4*)&b[4] = *(const float4*)&sB[kk][prB + 4];
#pragma unroll
      for (int i = 0; i < 8; ++i)
#pragma unroll
        for (int j = 0; j < 8; ++j) acc[i][j] += a[i] * b[j];
    }
    __syncthreads();
  }

  if (DIST) {
    _Float16* Ch = (_Float16*)Cout;
#pragma unroll
    for (int i = 0; i < 8; ++i) {
      int gr = row0 + ty * 8 + i;
      float xa = xxA[gr];
      h8 o;
#pragma unroll
      for (int j = 0; j < 8; ++j) {
        int gc = col0 + tx * 8 + j;
        o[j] = (_Float16)(2.f * acc[i][j] - xa - xxB[gc]);
      }
      *(h8*)&Ch[(size_t)gr * ldc + col0 + tx * 8] = o;
    }
  } else {
    float* Cf = (float*)Cout;
#pragma unroll
    for (int i = 0; i < 8; ++i) {
      int gr = row0 + ty * 8 + i;
#pragma unroll
      for (int jq = 0; jq < 2; ++jq) {
        float4 o;
#pragma unroll
        for (int j = 0; j < 4; ++j) ((float*)&o)[j] = acc[i][jq * 4 + j];
        *(float4*)&Cf[(size_t)gr * ldc + col0 + tx * 8 + jq * 4] = o;
      }
    }
  }
}

// ---------------- split-bf16 MFMA symmetric dist: lower-triangle tiles, mirrored write ----
// <x,y> = hi.hi + hi.lo + lo.hi (3 chained bf16 MFMAs, fp32 acc; lo.lo term ~2^-16 dropped).
// Epilogue: fp16 tile in LDS (rows padded to 136 u16), coalesced h8 writes both orientations.
// grid (ntile, nbatch). Fragment maps identical to fc_mfma (m89-verified).
// LDS layout: 4 slabs of 5120 u16 at offsets a*5120 (Ahi, Alo, Bhi, Blo), rows of 40 u16.
__global__ __launch_bounds__(256) void dist_sym_mfma_kernel(const u16* __restrict__ Xhi,
                                                            const u16* __restrict__ Xlo, int K,
                                                            const float* __restrict__ xx,
                                                            _Float16* __restrict__ dist,
                                                            size_t dstride) {
  __shared__ __align__(16) u16 smem[20544];  // staging 4x128x40 (40960 B) / tile 128x136 (34816 B)
  int t = threadIdx.x;
  int lane = t & 63, wave = t >> 6;
  const u16* xh = Xhi + (size_t)blockIdx.y * NPTS * K;
  const u16* xl = Xlo + (size_t)blockIdx.y * NPTS * K;
  const float* xxv = xx + (size_t)blockIdx.y * NPTS;
  _Float16* db = dist + (size_t)blockIdx.y * dstride;
  int l = blockIdx.x;
  int bi = (int)((sqrtf(8.f * (float)l + 1.f) - 1.f) * 0.5f);
  while ((bi + 1) * (bi + 2) / 2 <= l) ++bi;
  while (bi * (bi + 1) / 2 > l) --bi;
  int bj = l - bi * (bi + 1) / 2;
  int row0 = bi * 128, col0 = bj * 128;
  int wr = (wave >> 1) * 64, wc = (wave & 1) * 64;
  int m = lane & 15, q = lane >> 4;
  f32x4 acc[4][4];
#pragma unroll
  for (int i = 0; i < 4; ++i)
#pragma unroll
    for (int j = 0; j < 4; ++j) acc[i][j] = (f32x4){0.f, 0.f, 0.f, 0.f};

  for (int k0 = 0; k0 < K; k0 += 32) {
#pragma unroll
    for (int it = 0; it < 8; ++it) {
      int e = t + it * 256;
      int a = e >> 9, idx = e & 511;
      int r = idx >> 2, qq = idx & 3;
      const u16* src = (a == 0 || a == 2) ? xh : xl;
      int base = (a < 2) ? row0 : col0;
      *(uint4*)&smem[a * 5120 + r * 40 + qq * 8] =
          *(const uint4*)&src[(size_t)(base + r) * K + k0 + qq * 8];
    }
    __syncthreads();
    bf16x8 ah[4], al[4], bh[4], bl[4];
#pragma unroll
    for (int i = 0; i < 4; ++i) {
      ah[i] = *(const bf16x8*)&smem[0 * 5120 + (wr + i * 16 + m) * 40 + q * 8];
      al[i] = *(const bf16x8*)&smem[1 * 5120 + (wr + i * 16 + m) * 40 + q * 8];
    }
#pragma unroll
    for (int j = 0; j < 4; ++j) {
      bh[j] = *(const bf16x8*)&smem[2 * 5120 + (wc + j * 16 + m) * 40 + q * 8];
      bl[j] = *(const bf16x8*)&smem[3 * 5120 + (wc + j * 16 + m) * 40 + q * 8];
    }
#pragma unroll
    for (int i = 0; i < 4; ++i)
#pragma unroll
      for (int j = 0; j < 4; ++j) {
        acc[i][j] = __builtin_amdgcn_mfma_f32_16x16x32_bf16(ah[i], bh[j], acc[i][j], 0, 0, 0);
        acc[i][j] = __builtin_amdgcn_mfma_f32_16x16x32_bf16(ah[i], bl[j], acc[i][j], 0, 0, 0);
        acc[i][j] = __builtin_amdgcn_mfma_f32_16x16x32_bf16(al[i], bh[j], acc[i][j], 0, 0, 0);
      }
    __syncthreads();
  }

  // DIST transform -> fp16 LDS tile (reuses staging smem; all reads drained by loop-end sync)
  _Float16* tile = (_Float16*)smem;
  {
    float xbv[4];
#pragma unroll
    for (int j = 0; j < 4; ++j) xbv[j] = xxv[col0 + wc + j * 16 + m];
#pragma unroll
    for (int i = 0; i < 4; ++i)
#pragma unroll
      for (int reg = 0; reg < 4; ++reg) {
        int r = wr + i * 16 + q * 4 + reg;
        float xa = xxv[row0 + r];
#pragma unroll
        for (int j = 0; j < 4; ++j)
          tile[r * 136 + wc + j * 16 + m] = (_Float16)(2.f * acc[i][j][reg] - xa - xbv[j]);
      }
  }
  __syncthreads();
  // direct tile (row0, col0): coalesced h8 per 8-col segment
  for (int e = t; e < 2048; e += 256) {
    int r = e >> 4, seg = e & 15;
    *(h8*)&db[(size_t)(row0 + r) * NPTS + col0 + seg * 8] = *(const h8*)&tile[r * 136 + seg * 8];
  }
  // mirrored tile (col0, row0): transposed LDS reads, coalesced global h8 writes
  if (bi != bj) {
    for (int e = t; e < 2048; e += 256) {
      int c = e >> 4, seg = e & 15;
      h8 o;
#pragma unroll
      for (int i = 0; i < 8; ++i) o[i] = tile[(seg * 8 + i) * 136 + c];
      *(h8*)&db[(size_t)(col0 + c) * NPTS + row0 + seg * 8] = o;
    }
  }
}

// ---------------- bf16 MFMA FC: C[8192x1024] = A[8192x512] * B[1024x512]^T ----------------
// Epilogue additionally emits per-block fp64 column sum/sumsq partials (replaces colstats):
// block (cx,ry) owns rows [ry*128,+128) x cols [cx*128,+128); writes pbuf[ry*2048 + col] (sum)
// and pbuf[ry*2048 + 1024 + col] (sumsq) — same layout bn_reduce_finalize(nblk=64) consumes.
__global__ __launch_bounds__(256) void fc_mfma_kernel(const u16* __restrict__ A,
                                                      const u16* __restrict__ B,
                                                      float* __restrict__ C,
                                                      double* __restrict__ pbuf) {
  __shared__ u16 sA[128][56];
  __shared__ u16 sB[128][56];
  __shared__ double sred1[4][64];
  __shared__ double sred2[4][64];
  int t = threadIdx.x;
  int lane = t & 63, wave = t >> 6;
  int row0 = blockIdx.y * 128, col0 = blockIdx.x * 128;
  int wr = (wave >> 1) * 64, wc = (wave & 1) * 64;
  int m = lane & 15, q = lane >> 4;
  f32x4 acc[4][4];
#pragma unroll
  for (int i = 0; i < 4; ++i)
#pragma unroll
    for (int j = 0; j < 4; ++j) acc[i][j] = (f32x4){0.f, 0.f, 0.f, 0.f};
  for (int k0 = 0; k0 < 512; k0 += 32) {
#pragma unroll
    for (int it = 0; it < 2; ++it) {
      int i = t + it * 256;
      int r = i >> 2, ch = (i & 3) * 8;
      *(uint4*)&sA[r][ch] = *(const uint4*)&A[(size_t)(row0 + r) * 512 + k0 + ch];
      *(uint4*)&sB[r][ch] = *(const uint4*)&B[(size_t)(col0 + r) * 512 + k0 + ch];
    }
    __syncthreads();
    bf16x8 af[4], bf[4];
#pragma unroll
    for (int i = 0; i < 4; ++i) af[i] = *(const bf16x8*)&sA[wr + i * 16 + m][q * 8];
#pragma unroll
    for (int j = 0; j < 4; ++j) bf[j] = *(const bf16x8*)&sB[wc + j * 16 + m][q * 8];
#pragma unroll
    for (int i = 0; i < 4; ++i)
#pragma unroll
      for (int j = 0; j < 4; ++j)
        acc[i][j] = __builtin_amdgcn_mfma_f32_16x16x32_bf16(af[i], bf[j], acc[i][j], 0, 0, 0);
    __syncthreads();
  }
#pragma unroll
  for (int i = 0; i < 4; ++i)
#pragma unroll
    for (int j = 0; j < 4; ++j)
#pragma unroll
      for (int reg = 0; reg < 4; ++reg)
        C[(size_t)(row0 + wr + i * 16 + q * 4 + reg) * 1024 + col0 + wc + j * 16 + m] =
            acc[i][j][reg];

  // ---- fused column stats (fp64): per-thread 16 rows, q-group shuffle, wave-pair combine ----
#pragma unroll
  for (int j = 0; j < 4; ++j) {
    double s1 = 0.0, s2 = 0.0;
#pragma unroll
    for (int i = 0; i < 4; ++i)
#pragma unroll
      for (int reg = 0; reg < 4; ++reg) {
        double v = (double)acc[i][j][reg];
        s1 += v;
        s2 += v * v;
      }
    // reduce across q (lanes q*16+m, q=0..3): xor 16 then 32 keeps m fixed
    s1 += __shfl_xor(s1, 16);
    s2 += __shfl_xor(s2, 16);
    s1 += __shfl_xor(s1, 32);
    s2 += __shfl_xor(s2, 32);
    if (q == 0) {
      sred1[wave][j * 16 + m] = s1;
      sred2[wave][j * 16 + m] = s2;
    }
  }
  __syncthreads();
  if (t < 128) {
    int p = t >> 6, u = t & 63;  // p: wc half (waves p and p+2), u = j*16+m
    double a = sred1[p][u] + sred1[p + 2][u];
    double b = sred2[p][u] + sred2[p + 2][u];
    int gcol = col0 + p * 64 + u;
    pbuf[(size_t)blockIdx.y * 2048 + gcol] = a;
    pbuf[(size_t)blockIdx.y * 2048 + 1024 + gcol] = b;
  }
}

// ---------------- shared top-k selection helpers ----------------
// fp32 select machinery (round-6): rescore+sort+merge in fp32. Ordering flips vs fp64
// require exact-distance ties within ~1e-7 relative — same tie-window class as the
// reference's own fp32 einsum+top_k. Tie-break (value, then smaller index) unchanged.
__device__ inline bool comp_less(float v, int i, float ov, int oi) {
  return (v < ov) || (v == ov && i > oi);
}

// ---------------- fast top-k: threshold filter (fp16 dist) + fp32 rescore + bitonic sort ---
template <int C>
__global__ __launch_bounds__(256) void topk_fast_kernel(const _Float16* __restrict__ dist,
                                                        size_t dstride,
                                                        const float* __restrict__ Xb,
                                                        size_t xstride, int lda,
                                                        int* __restrict__ idxout, size_t istride,
                                                        int n0, int rows) {
  __shared__ int scand[4][MAXCAND];
  int wave = threadIdx.x >> 6, lane = threadIdx.x & 63;
  int row = blockIdx.x * 4 + wave;
  if (row >= rows) return;
  const _Float16* distb = dist + (size_t)blockIdx.y * dstride;
  const float* Xbb = Xb + (size_t)blockIdx.y * xstride;
  int* idxb = idxout + (size_t)blockIdx.y * istride;
  const _Float16* d = distb + (size_t)row * NPTS;
  float v[16][4];
  float lmax = -__builtin_inff();
#pragma unroll
  for (int s = 0; s < 16; ++s) {
    h4 hv = *(const h4*)&d[s * 256 + lane * 4];
#pragma unroll
    for (int c = 0; c < 4; ++c) {
      v[s][c] = (float)hv[c];
      lmax = fmaxf(lmax, v[s][c]);
    }
  }

  float sv = lmax;
  for (int k = 2; k <= 64; k <<= 1) {
    for (int j = k >> 1; j > 0; j >>= 1) {
      float ov = __shfl_xor(sv, j);
      bool up = ((lane & k) == 0);
      bool lower = ((lane & j) == 0);
      bool mineLess = sv < ov;
      bool keepMine = (up == lower) ? mineLess : !mineLess;
      sv = keepMine ? sv : ov;
    }
  }
  float T = __shfl(sv, 44);

  int myCnt = 0;
#pragma unroll
  for (int s = 0; s < 16; ++s)
#pragma unroll
    for (int c = 0; c < 4; ++c) myCnt += (v[s][c] >= T) ? 1 : 0;
  int ofs = myCnt;
  for (int dlt = 1; dlt < 64; dlt <<= 1) {
    int o = __shfl_up(ofs, dlt);
    if (lane >= dlt) ofs += o;
  }
  int total = __shfl(ofs, 63);
  ofs -= myCnt;
  int w = ofs;
#pragma unroll
  for (int s = 0; s < 16; ++s)
#pragma unroll
    for (int c = 0; c < 4; ++c) {
      if (v[s][c] >= T) {
        if (w < MAXCAND) scand[wave][w] = s * 256 + lane * 4 + c;
        ++w;
      }
    }
  int cnt = imin(total, MAXCAND);
  int gn = n0 + row;
  const float* crow = Xbb + (size_t)gn * lda;
  int nch = (cnt + 63) >> 6;

  float runV = -__builtin_inff();
  int runI = 0x7fffffff;
  for (int ch = 0; ch < nch; ++ch) {
    int slot = ch * 64 + lane;
    int m = (slot < cnt) ? scand[wave][slot] : -1;
    float val = -__builtin_inff();
    int vi = 0x7fffffff;
    if (m >= 0) {
      const float* mrow = Xbb + (size_t)m * lda;
      float d0 = 0.f, d1 = 0.f, d2 = 0.f, d3 = 0.f;
#pragma unroll
      for (int c = 0; c < C; c += 4) {
        float4 a = *(const float4*)&crow[c];
        float4 b = *(const float4*)&mrow[c];
        float f0 = a.x - b.x;
        float f1 = a.y - b.y;
        float f2 = a.z - b.z;
        float f3 = a.w - b.w;
        d0 = fmaf(f0, f0, d0);
        d1 = fmaf(f1, f1, d1);
        d2 = fmaf(f2, f2, d2);
        d3 = fmaf(f3, f3, d3);
      }
      val = -((d0 + d1) + (d2 + d3));
      vi = m;
    }
    for (int k = 2; k <= 64; k <<= 1) {
      for (int j = k >> 1; j > 0; j >>= 1) {
        float ov = __shfl_xor(val, j);
        int oi = __shfl_xor(vi, j);
        bool up = ((lane & k) == 0);
        bool lower = ((lane & j) == 0);
        bool mineLess = comp_less(val, vi, ov, oi);
        bool keepMine = (up == lower) ? mineLess : !mineLess;
        if (!keepMine) { val = ov; vi = oi; }
      }
    }
    if (ch == 0) {
      runV = val;
      runI = vi;
    } else {
      float rv = __shfl(val, 63 - lane);
      int ri = __shfl(vi, 63 - lane);
      if (comp_less(runV, runI, rv, ri)) { runV = rv; runI = ri; }
      for (int j = 32; j > 0; j >>= 1) {
        float ov = __shfl_xor(runV, j);
        int oi = __shfl_xor(runI, j);
        bool lower = ((lane & j) == 0);
        bool mineLess = comp_less(runV, runI, ov, oi);
        bool keepMine = lower ? mineLess : !mineLess;
        if (!keepMine) { runV = ov; runI = oi; }
      }
    }
  }
  if (lane >= 44) idxb[(size_t)gn * KNN + (63 - lane)] = runI;
}

// ---------------- fused layer-1 kNN (C=3): whole point set in LDS ----------------
// 512 threads = 8 waves/block, 8 rows/block, register-cached v[16][4] per wave
// (~88 VGPR -> 4 waves/SIMD band). LDS = 48K xyz + 4K u16 scand = 52K. fp32 select
// machinery (see comp_less note). NO min-waves bound (forcing 8/EU clamps VGPR to 32
// -> 600 MB/dispatch scratch spill).
__global__ __launch_bounds__(512) void dist3_topk_kernel(const float* __restrict__ Xb,
                                                         int* __restrict__ idxout) {
  __shared__ float xs[NPTS], ys[NPTS], zs[NPTS];
  __shared__ u16 scand[8][MAXCAND];
  int t = threadIdx.x;
  const float* Xbb = Xb + (size_t)blockIdx.y * NPTS * 3;
  for (int i = t; i < NPTS * 3; i += 512) {
    int n = i / 3, c = i - n * 3;
    float v = Xbb[i];
    if (c == 0) xs[n] = v;
    else if (c == 1) ys[n] = v;
    else zs[n] = v;
  }
  __syncthreads();
  int wave = t >> 6, lane = t & 63;
  int row = blockIdx.x * 8 + wave;
  float cx = xs[row], cy = ys[row], cz = zs[row];
  float v[16][4];
  float lmax = -__builtin_inff();
#pragma unroll
  for (int s = 0; s < 16; ++s)
#pragma unroll
    for (int c = 0; c < 4; ++c) {
      int m = s * 256 + c * 64 + lane;
      float dx = cx - xs[m], dy = cy - ys[m], dz = cz - zs[m];
      float dv = -(dx * dx + dy * dy + dz * dz);
      v[s][c] = dv;
      lmax = fmaxf(lmax, dv);
    }

  float sv = lmax;
  for (int k = 2; k <= 64; k <<= 1) {
    for (int j = k >> 1; j > 0; j >>= 1) {
      float ov = __shfl_xor(sv, j);
      bool up = ((lane & k) == 0);
      bool lower = ((lane & j) == 0);
      bool mineLess = sv < ov;
      bool keepMine = (up == lower) ? mineLess : !mineLess;
      sv = keepMine ? sv : ov;
    }
  }
  float T = __shfl(sv, 44);

  int myCnt = 0;
#pragma unroll
  for (int s = 0; s < 16; ++s)
#pragma unroll
    for (int c = 0; c < 4; ++c) myCnt += (v[s][c] >= T) ? 1 : 0;
  int ofs = myCnt;
  for (int dlt = 1; dlt < 64; dlt <<= 1) {
    int o = __shfl_up(ofs, dlt);
    if (lane >= dlt) ofs += o;
  }
  int total = __shfl(ofs, 63);
  ofs -= myCnt;
  int w = ofs;
#pragma unroll
  for (int s = 0; s < 16; ++s)
#pragma unroll
    for (int c = 0; c < 4; ++c) {
      if (v[s][c] >= T) {
        if (w < MAXCAND) scand[wave][w] = (u16)(s * 256 + c * 64 + lane);
        ++w;
      }
    }
  int cnt = imin(total, MAXCAND);
  int nch = (cnt + 63) >> 6;

  float runV = -__builtin_inff();
  int runI = 0x7fffffff;
  for (int ch = 0; ch < nch; ++ch) {
    int slot = ch * 64 + lane;
    int m = (slot < cnt) ? (int)scand[wave][slot] : -1;
    float val = -__builtin_inff();
    int vi = 0x7fffffff;
    if (m >= 0) {
      float dx = cx - xs[m];
      float dy = cy - ys[m];
      float dz = cz - zs[m];
      val = -fmaf(dx, dx, fmaf(dy, dy, dz * dz));
      vi = m;
    }
    for (int k = 2; k <= 64; k <<= 1) {
      for (int j = k >> 1; j > 0; j >>= 1) {
        float ov = __shfl_xor(val, j);
        int oi = __shfl_xor(vi, j);
        bool up = ((lane & k) == 0);
        bool lower = ((lane & j) == 0);
        bool mineLess = comp_less(val, vi, ov, oi);
        bool keepMine = (up == lower) ? mineLess : !mineLess;
        if (!keepMine) { val = ov; vi = oi; }
      }
    }
    if (ch == 0) {
      runV = val;
      runI = vi;
    } else {
      float rv = __shfl(val, 63 - lane);
      int ri = __shfl(vi, 63 - lane);
      if (comp_less(runV, runI, rv, ri)) { runV = rv; runI = ri; }
      for (int j = 32; j > 0; j >>= 1) {
        float ov = __shfl_xor(runV, j);
        int oi = __shfl_xor(runI, j);
        bool lower = ((lane & j) == 0);
        bool mineLess = comp_less(runV, runI, ov, oi);
        bool keepMine = lower ? mineLess : !mineLess;
        if (!keepMine) { runV = ov; runI = oi; }
      }
    }
  }
  if (lane >= 44)
    idxout[((size_t)blockIdx.y * NPTS + row) * KNN + (63 - lane)] = runI;
}

// ---------------- gather-max + per-block fp64 BN partial stats ----------------
template <int NO>
__global__ __launch_bounds__(256) void gathermax_kernel(const float* __restrict__ PQ,
                                                        const int* __restrict__ idx,
                                                        float* __restrict__ hmax, int O,
                                                        double* __restrict__ pbuf) {
  __shared__ double sh1[4][256];
  __shared__ double sh2[4][256];
  int t = threadIdx.x;
  int wave = t >> 6, lane = t & 63;
  int pt = blockIdx.x * 4 + wave;
  int b = pt >> 12;
  int O2 = 2 * O;
  int iv = idx[(size_t)pt * KNN + (lane % KNN)];
  const float* Qp = PQ + (size_t)pt * O2 + O + lane * NO;
  float q[NO], mx[NO];
  double s1[NO], s2[NO];
#pragma unroll
  for (int c = 0; c < NO; ++c) {
    q[c] = Qp[c];
    mx[c] = -__builtin_inff();
    s1[c] = 0.0;
    s2[c] = 0.0;
  }
#pragma unroll
  for (int k = 0; k < KNN; ++k) {
    int m = __shfl(iv, k);
    const float* Pp = PQ + ((size_t)(b << 12) + m) * O2 + lane * NO;
    float p[NO];
#pragma unroll
    for (int c = 0; c < NO; ++c) p[c] = Pp[c];
#pragma unroll
    for (int c = 0; c < NO; ++c) {
      float h = p[c] + q[c];
      mx[c] = fmaxf(mx[c], h);
      double hd = (double)h;
      s1[c] += hd;
      s2[c] += hd * hd;
    }
  }
  float* Hp = hmax + (size_t)pt * O + lane * NO;
#pragma unroll
  for (int c = 0; c < NO; ++c) {
    Hp[c] = mx[c];
    sh1[wave][lane * NO + c] = s1[c];
    sh2[wave][lane * NO + c] = s2[c];
  }
  __syncthreads();
  if (t < O) {
    double a = 0.0, bb = 0.0;
#pragma unroll
    for (int w = 0; w < 4; ++w) {
      a += sh1[w][t];
      bb += sh2[w][t];
    }
    pbuf[(size_t)blockIdx.x * O2 + t] = a;
    pbuf[(size_t)blockIdx.x * O2 + O + t] = bb;
  }
}

// ---------------- deterministic parallel fp64 BN reduce + finalize ----------------
__global__ __launch_bounds__(256) void bn_reduce_finalize(const double* __restrict__ pbuf,
                                                          int nblk, int O,
                                                          const float* __restrict__ g,
                                                          const float* __restrict__ bb,
                                                          double invcount,
                                                          float* __restrict__ s_out,
                                                          float* __restrict__ t_out) {
  __shared__ double sh1[256];
  __shared__ double sh2[256];
  int o = blockIdx.x;
  int t = threadIdx.x;
  double s1 = 0.0, s2 = 0.0;
  for (int blk = t; blk < nblk; blk += 256) {
    s1 += pbuf[(size_t)blk * 2 * O + o];
    s2 += pbuf[(size_t)blk * 2 * O + O + o];
  }
  sh1[t] = s1;
  sh2[t] = s2;
  __syncthreads();
  for (int s = 128; s > 0; s >>= 1) {
    if (t < s) {
      sh1[t] += sh1[t + s];
      sh2[t] += sh2[t + s];
    }
    __syncthreads();
  }
  if (t == 0) {
    double mean = sh1[0] * invcount;
    double var = sh2[0] * invcount - mean * mean;
    double s = (double)g[o] / sqrt(var + BNEPS);
    s_out[o] = (float)s;
    t_out[o] = (float)((double)bb[o] - mean * s);
  }
}

// y = leaky(hmax*s+t) into feat column slice (fp32) + featbf (bf16, fused conversion)
__global__ void apply_kernel(const float* __restrict__ hmax, const float* __restrict__ s,
                             const float* __restrict__ tt, float* __restrict__ feat,
                             u16* __restrict__ featbf, int colOff, int logO, int total) {
  int i = blockIdx.x * 256 + threadIdx.x;
  if (i >= total) return;
  int O = 1 << logO;
  int o = i & (O - 1);
  int pp = i >> logO;
  float v = hmax[i] * s[o] + tt[o];
  float r = v > 0.f ? v : SLOPE * v;
  size_t di = (size_t)pp * 512 + colOff + o;
  feat[di] = r;
  featbf[di] = f2bf(r);
}

// out[b][o][n] = leaky(h5[b][n][o]*s+t)
__global__ void out_kernel(const float* __restrict__ h5, const float* __restrict__ s,
                           const float* __restrict__ tt, float* __restrict__ out) {
  __shared__ float tile[32][33];
  int b = blockIdx.z;
  int n0 = blockIdx.x * 32, o0 = blockIdx.y * 32;
  int t = threadIdx.x;
  for (int e = t; e < 1024; e += 256) {
    int rn = e >> 5, co = e & 31;
    int o = o0 + co;
    float v = h5[((size_t)b * NPTS + n0 + rn) * 1024 + o] * s[o] + tt[o];
    tile[rn][co] = v > 0.f ? v : SLOPE * v;
  }
  __syncthreads();
  for (int e = t; e < 1024; e += 256) {
    int ro = e >> 5, cn = e & 31;
    out[((size_t)b * 1024 + o0 + ro) * NPTS + n0 + cn] = tile[cn][ro];
  }
}

// ---------------- host ----------------
extern "C" void kernel_launch(void* const* d_in, const int* in_sizes, int n_in,
                              void* d_out, int out_size, void* d_ws, size_t ws_size,
                              hipStream_t stream) {
  const float* x = (const float*)d_in[0];
  const float* Wm[5] = {(const float*)d_in[1], (const float*)d_in[4], (const float*)d_in[7],
                        (const float*)d_in[10], (const float*)d_in[13]};
  const float* gv[5] = {(const float*)d_in[2], (const float*)d_in[5], (const float*)d_in[8],
                        (const float*)d_in[11], (const float*)d_in[14]};
  const float* bvv[5] = {(const float*)d_in[3], (const float*)d_in[6], (const float*)d_in[9],
                         (const float*)d_in[12], (const float*)d_in[15]};
  float* out = (float*)d_out;

  char* wsb = (char*)d_ws;
  size_t off = 0;
  auto alloc = [&](size_t bytes) -> char* {
    off = (off + 255) & ~(size_t)255;
    char* p = wsb + off;
    off += bytes;
    return p;
  };
  float* xb = (float*)alloc((size_t)BATCH * NPTS * 3 * 4);
  float* xxb = (float*)alloc((size_t)BATCH * NPTS * 4);
  int* idxb = (int*)alloc((size_t)BATCH * NPTS * KNN * 4);
  float* feat = (float*)alloc((size_t)BATCH * NPTS * 512 * 4);
  float* hmax = (float*)alloc((size_t)BATCH * NPTS * 256 * 4);
  float* h5 = (float*)alloc((size_t)BATCH * NPTS * 1024 * 4);
  float* PQ = h5;  // alias: PQ used per-layer, h5 only needed after
  float* U1 = (float*)alloc(3 * 128 * 4);
  float* U2 = (float*)alloc(64 * 128 * 4);
  float* U3 = (float*)alloc(64 * 256 * 4);
  float* U4 = (float*)alloc(128 * 512 * 4);
  u16* featbf = (u16*)alloc((size_t)BATCH * NPTS * 512 * 2);
  u16* w5bf = (u16*)alloc((size_t)1024 * 512 * 2);
  u16* xhi = (u16*)alloc((size_t)BATCH * NPTS * 128 * 2);
  u16* xlo = (u16*)alloc((size_t)BATCH * NPTS * 128 * 2);
  double* pbuf = (double*)alloc((size_t)2048 * 512 * 8);
  float* stv = (float*)alloc(3072 * 4);
  off = (off + 255) & ~(size_t)255;
  size_t avail = (ws_size > off) ? (ws_size - off) : 0;
  size_t slab = (size_t)NPTS * NPTS * 2;              // one batch's fp16 dist matrix
  int nbfit = (int)imin((int)(avail / slab), BATCH);  // 0, 1, or 2 slabs fit
  size_t rmax = avail / ((size_t)NPTS * 2);
  int R;
  if (rmax >= NPTS) R = NPTS;
  else {
    R = (int)(rmax & ~(size_t)127);
    if (R < 128) R = 128;
  }
  _Float16* distbuf = (_Float16*)(wsb + off);

  float* sv[5] = {stv + 0, stv + 128, stv + 256, stv + 512, stv + 1024};
  float* tv[5] = {stv + 64, stv + 192, stv + 384, stv + 768, stv + 2048};
  float* Us[4] = {U1, U2, U3, U4};
  const int Cs[4] = {3, 64, 64, 128};
  const int Osz[4] = {64, 64, 128, 256};
  const int ntile = (NPTS / 128) * (NPTS / 128 + 1) / 2;  // 528

  xtrans_kernel<<<(BATCH * 3 * NPTS + 255) / 256, 256, 0, stream>>>(x, xb);
  for (int l = 0; l < 4; ++l)
    uprep_kernel<<<(Cs[l] * Osz[l] + 255) / 256, 256, 0, stream>>>(Wm[l], Us[l], Osz[l], Cs[l]);
  tobf16_kernel<<<(1024 * 512 / 4 + 255) / 256, 256, 0, stream>>>(Wm[4], w5bf, 1024 * 512 / 4);

  auto launch_topk = [&](int C, dim3 grid, const _Float16* db, size_t dstride, const float* Xb,
                         size_t xstride, int lda, int* idxo, size_t istride, int n0, int rows) {
    if (C == 64)
      topk_fast_kernel<64><<<grid, 256, 0, stream>>>(db, dstride, Xb, xstride, lda, idxo, istride,
                                                     n0, rows);
    else
      topk_fast_kernel<128><<<grid, 256, 0, stream>>>(db, dstride, Xb, xstride, lda, idxo, istride,
                                                      n0, rows);
  };

  auto knn = [&](const float* Xbase, int lda, int C) {
    xx_kernel<<<(BATCH * NPTS + 255) / 256, 256, 0, stream>>>(Xbase, lda, C, xxb);
    size_t selems = (size_t)NPTS * NPTS;
    if (nbfit >= 1) {
      int ngroups = BATCH * NPTS * (C / 4);
      tosplit_kernel<<<(ngroups + 255) / 256, 256, 0, stream>>>(Xbase, lda, C, xhi, xlo, ngroups);
    }
    if (nbfit >= BATCH) {
      dist_sym_mfma_kernel<<<dim3(ntile, BATCH), 256, 0, stream>>>(xhi, xlo, C, xxb, distbuf,
                                                                   selems);
      launch_topk(C, dim3(NPTS / 4, BATCH), distbuf, selems, Xbase, (size_t)NPTS * lda, lda, idxb,
                  (size_t)NPTS * KNN, 0, NPTS);
    } else if (nbfit >= 1) {
      for (int b = 0; b < BATCH; ++b) {
        const float* Xb = Xbase + (size_t)b * NPTS * lda;
        dist_sym_mfma_kernel<<<dim3(ntile, 1), 256, 0, stream>>>(
            xhi + (size_t)b * NPTS * C, xlo + (size_t)b * NPTS * C, C, xxb + (size_t)b * NPTS,
            distbuf, 0);
        launch_topk(C, dim3(NPTS / 4, 1), distbuf, 0, Xb, 0, lda, idxb + (size_t)b * NPTS * KNN, 0,
                    0, NPTS);
      }
    } else {
      for (int b = 0; b < BATCH; ++b) {
        const float* Xb = Xbase + (size_t)b * NPTS * lda;
        for (int n0 = 0; n0 < NPTS; n0 += R) {
          int rows = imin(R, NPTS - n0);
          gemm128<true, true><<<dim3(NPTS / 128, rows / 128), 256, 0, stream>>>(
              Xb + (size_t)n0 * lda, lda, Xb, lda, (void*)distbuf, NPTS, C,
              xxb + (size_t)b * NPTS + n0, xxb + (size_t)b * NPTS);
          launch_topk(C, dim3(rows / 4, 1), distbuf, 0, Xb, 0, lda, idxb + (size_t)b * NPTS * KNN,
                      0, n0, rows);
        }
      }
    }
  };

  auto edge = [&](int li, const float* Xbase, int lda, int C, int O, int colOff) {
    if (li == 0) {
      dist3_topk_kernel<<<dim3(NPTS / 8, BATCH), 512, 0, stream>>>(Xbase, idxb);
    } else {
      knn(Xbase, lda, C);
    }
    int O2 = 2 * O;
    gemm128<false, false><<<dim3(O2 / 128, BATCH * NPTS / 128), 256, 0, stream>>>(
        Xbase, lda, Us[li], O2, (void*)PQ, O2, C, nullptr, nullptr);
    int nblk = BATCH * NPTS / 4;
    if (O == 64)
      gathermax_kernel<1><<<nblk, 256, 0, stream>>>(PQ, idxb, hmax, O, pbuf);
    else if (O == 128)
      gathermax_kernel<2><<<nblk, 256, 0, stream>>>(PQ, idxb, hmax, O, pbuf);
    else
      gathermax_kernel<4><<<nblk, 256, 0, stream>>>(PQ, idxb, hmax, O, pbuf);
    bn_reduce_finalize<<<O, 256, 0, stream>>>(pbuf, nblk, O, gv[li], bvv[li],
                                              1.0 / ((double)BATCH * NPTS * KNN), sv[li], tv[li]);
    int logO = (O == 64) ? 6 : (O == 128) ? 7 : 8;
    int total = BATCH * NPTS * O;
    apply_kernel<<<(total + 255) / 256, 256, 0, stream>>>(hmax, sv[li], tv[li], feat, featbf,
                                                          colOff, logO, total);
  };

  edge(0, xb, 3, 3, 64, 0);
  edge(1, feat, 512, 64, 64, 64);
  edge(2, feat + 64, 512, 64, 128, 128);
  edge(3, feat + 128, 512, 128, 256, 256);

  fc_mfma_kernel<<<dim3(1024 / 128, BATCH * NPTS / 128), 256, 0, stream>>>(featbf, w5bf, h5, pbuf);
  bn_reduce_finalize<<<1024, 256, 0, stream>>>(pbuf, 64, 1024, gv[4], bvv[4],
                                               1.0 / ((double)BATCH * NPTS), sv[4], tv[4]);
  out_kernel<<<dim3(NPTS / 32, 1024 / 32, BATCH), 256, 0, stream>>>(h5, sv[4], tv[4], out);
}